// Round 1
// baseline (11490.303 us; speedup 1.0000x reference)
//
#include <hip/hip_runtime.h>

#define B_ 4
#define N_ 65536
#define CIN_ 64
#define CO_ 128
#define R_ 32
#define RRR_ 32768
#define GROUPS_ 8
#define CPG_ 16

// ---- workspace layout (float offsets) ----
// nc      [B][3][N]      786432
// vidx    [B][N] (int)   262144
// cnt     [B][RRR]       131072
// grid    [B][64][RRR]   8388608   (sum -> mean in place)
// buf1    [B][128][RRR]  16777216  (conv1 out -> gn1+silu in place -> later h_t [B][RRR][128])
// buf2    [B][128][RRR]  16777216  (conv2 out)
// bstats  [B][4]         16        (mean x3, denom)
// gstats  [3][B][8][2]   192       (mean, rstd per layer/batch/group)
static const size_t OFF_NC     = 0;
static const size_t OFF_VIDX   = 786432;
static const size_t OFF_CNT    = 1048576;
static const size_t OFF_GRID   = 1179648;
static const size_t OFF_BUF1   = 9568256;
static const size_t OFF_BUF2   = 26345472;
static const size_t OFF_BSTATS = 43122688;
static const size_t OFF_GSTATS = 43122704;

// ---------------- kernel 1: per-batch coord mean + max-norm ----------------
__global__ __launch_bounds__(256) void k_batch_stats(const float* __restrict__ coords,
                                                     float* __restrict__ bstats) {
    int b = blockIdx.x;
    int tid = threadIdx.x;
    __shared__ float red[256];
    __shared__ float meansh[3];
    const float* cb = coords + (size_t)b * 3 * N_;
    float s0 = 0.f, s1 = 0.f, s2 = 0.f;
    for (int n = tid; n < N_; n += 256) {
        s0 += cb[n]; s1 += cb[N_ + n]; s2 += cb[2 * N_ + n];
    }
    float svals[3] = {s0, s1, s2};
    for (int d = 0; d < 3; ++d) {
        red[tid] = svals[d];
        __syncthreads();
        for (int o = 128; o > 0; o >>= 1) {
            if (tid < o) red[tid] += red[tid + o];
            __syncthreads();
        }
        if (tid == 0) meansh[d] = red[0] / (float)N_;
        __syncthreads();
    }
    float m0 = meansh[0], m1 = meansh[1], m2 = meansh[2];
    float mx = 0.f;
    for (int n = tid; n < N_; n += 256) {
        float x = cb[n] - m0, y = cb[N_ + n] - m1, z = cb[2 * N_ + n] - m2;
        mx = fmaxf(mx, x * x + y * y + z * z);
    }
    red[tid] = mx;
    __syncthreads();
    for (int o = 128; o > 0; o >>= 1) {
        if (tid < o) red[tid] = fmaxf(red[tid], red[tid + o]);
        __syncthreads();
    }
    if (tid == 0) {
        bstats[b * 4 + 0] = m0;
        bstats[b * 4 + 1] = m1;
        bstats[b * 4 + 2] = m2;
        bstats[b * 4 + 3] = 2.0f * sqrtf(red[0]);
    }
}

// ---------------- kernel 2: normalized coords, voxel idx, counts ----------------
__global__ __launch_bounds__(256) void k_point_prep(const float* __restrict__ coords,
                                                    const float* __restrict__ bstats,
                                                    float* __restrict__ nc,
                                                    int* __restrict__ vidx,
                                                    float* __restrict__ cnt) {
    int gid = blockIdx.x * 256 + threadIdx.x;      // B*N
    int b = gid >> 16;
    int n = gid & (N_ - 1);
    float m[3] = {bstats[b * 4 + 0], bstats[b * 4 + 1], bstats[b * 4 + 2]};
    float den = bstats[b * 4 + 3];
    const float* cb = coords + (size_t)b * 3 * N_;
    int vi[3];
    #pragma unroll
    for (int d = 0; d < 3; ++d) {
        float cv = cb[(size_t)d * N_ + n];
        float t = (cv - m[d]) / den + 0.5f;
        t *= (float)R_;
        t = fminf(fmaxf(t, 0.0f), 31.0f);
        nc[((size_t)b * 3 + d) * N_ + n] = t;
        vi[d] = (int)rintf(t);
    }
    int flat = (vi[0] * 32 + vi[1]) * 32 + vi[2];
    vidx[(b << 16) + n] = flat;
    atomicAdd(&cnt[(b << 15) + flat], 1.0f);
}

// ---------------- kernel 3: scatter-add features ----------------
__global__ __launch_bounds__(256) void k_scatter(const float* __restrict__ feats,
                                                 const int* __restrict__ vidx,
                                                 float* __restrict__ gsum) {
    int gid = blockIdx.x * 256 + threadIdx.x;      // B*64*N
    int n = gid & (N_ - 1);
    int bc = gid >> 16;                            // b*64+c
    int b = bc >> 6;
    int idx = vidx[(b << 16) + n];
    atomicAdd(&gsum[(size_t)bc * RRR_ + idx], feats[gid]);
}

// ---------------- kernel 4: sum -> mean ----------------
__global__ __launch_bounds__(256) void k_gridmean(float* __restrict__ gsum,
                                                  const float* __restrict__ cnt) {
    int gid = blockIdx.x * 256 + threadIdx.x;      // B*64*RRR = 2^23
    int vox = gid & (RRR_ - 1);
    int b = gid >> 21;
    float c = cnt[(b << 15) + vox];
    gsum[gid] = gsum[gid] / fmaxf(c, 1.0f);
}

// ---------------- kernel 5: 3^3 conv, LDS tiles, 2 co/block, x4 register block ----------------
template <int CIN>
__global__ __launch_bounds__(256) void k_conv3d(const float* __restrict__ in,
                                                const float* __restrict__ w,
                                                const float* __restrict__ bias,
                                                float* __restrict__ out) {
    const int d0 = blockIdx.x;            // 0..31
    const int co0 = blockIdx.y * 2;       // 0..126
    const int b = blockIdx.z;
    const int tid = threadIdx.x;
    const int tx4 = (tid & 7) * 4;        // d2 base
    const int ty = tid >> 3;              // d1 (0..31)

    __shared__ float wl[2 * CIN * 27];
    __shared__ float il[3 * 34 * 35];     // padded row stride 35

    for (int i = tid; i < 2 * CIN * 27; i += 256)
        wl[i] = w[(size_t)co0 * CIN * 27 + i];

    float acc[2][4] = {{0.f, 0.f, 0.f, 0.f}, {0.f, 0.f, 0.f, 0.f}};
    const float* inb = in + (size_t)b * CIN * RRR_;

    for (int ci = 0; ci < CIN; ++ci) {
        __syncthreads();
        const float* inc = inb + (size_t)ci * RRR_;
        for (int i = tid; i < 3 * 34 * 34; i += 256) {
            int dz = i / (34 * 34);
            int rem = i - dz * 34 * 34;
            int yy = rem / 34;
            int xx = rem - yy * 34;
            int g0 = d0 + dz - 1;
            int g1 = yy - 1;
            int g2 = xx - 1;
            float v = 0.f;
            if ((unsigned)g0 < 32u && (unsigned)g1 < 32u && (unsigned)g2 < 32u)
                v = inc[(g0 * 32 + g1) * 32 + g2];
            il[dz * 1190 + yy * 35 + xx] = v;
        }
        __syncthreads();
        const float* wc0 = &wl[ci * 27];
        const float* wc1 = &wl[CIN * 27 + ci * 27];
        #pragma unroll
        for (int fz = 0; fz < 3; ++fz) {
            #pragma unroll
            for (int fy = 0; fy < 3; ++fy) {
                const float* rp = &il[fz * 1190 + (ty + fy) * 35 + tx4];
                float v[6];
                #pragma unroll
                for (int j = 0; j < 6; ++j) v[j] = rp[j];
                const int fb = (fz * 3 + fy) * 3;
                #pragma unroll
                for (int fx = 0; fx < 3; ++fx) {
                    float w0 = wc0[fb + fx], w1 = wc1[fb + fx];
                    #pragma unroll
                    for (int j = 0; j < 4; ++j) {
                        acc[0][j] = fmaf(v[fx + j], w0, acc[0][j]);
                        acc[1][j] = fmaf(v[fx + j], w1, acc[1][j]);
                    }
                }
            }
        }
    }
    #pragma unroll
    for (int c = 0; c < 2; ++c) {
        float bb = bias[co0 + c];
        float4 r;
        r.x = acc[c][0] + bb; r.y = acc[c][1] + bb;
        r.z = acc[c][2] + bb; r.w = acc[c][3] + bb;
        *(float4*)&out[((size_t)(b * CO_ + co0 + c)) * RRR_ + d0 * 1024 + ty * 32 + tx4] = r;
    }
}

// ---------------- kernel 6: GroupNorm stats (mean, rstd) ----------------
__global__ __launch_bounds__(256) void k_gn_stats(const float* __restrict__ x,
                                                  float* __restrict__ gstats,
                                                  int spatial, int layer) {
    int bg = blockIdx.x;                 // b*8+g
    int tid = threadIdx.x;
    const float4* base = (const float4*)(x + (size_t)bg * CPG_ * spatial);
    int cnt4 = CPG_ * spatial / 4;
    float s = 0.f, ss = 0.f;
    for (int i = tid; i < cnt4; i += 256) {
        float4 v = base[i];
        s += (v.x + v.y) + (v.z + v.w);
        ss += (v.x * v.x + v.y * v.y) + (v.z * v.z + v.w * v.w);
    }
    __shared__ float r1[256], r2[256];
    r1[tid] = s; r2[tid] = ss;
    __syncthreads();
    for (int o = 128; o > 0; o >>= 1) {
        if (tid < o) { r1[tid] += r1[tid + o]; r2[tid] += r2[tid + o]; }
        __syncthreads();
    }
    if (tid == 0) {
        float count = (float)(CPG_ * spatial);
        float mean = r1[0] / count;
        float var = r2[0] / count - mean * mean;
        gstats[(layer * 32 + bg) * 2 + 0] = mean;
        gstats[(layer * 32 + bg) * 2 + 1] = rsqrtf(var + 1e-5f);
    }
}

// ---------------- kernel 7: GN + SiLU in place (voxel layout) ----------------
__global__ __launch_bounds__(256) void k_gn_silu(float* __restrict__ x,
                                                 const float* __restrict__ gstats,
                                                 const float* __restrict__ scale,
                                                 const float* __restrict__ bias,
                                                 int layer) {
    int gid = blockIdx.x * 256 + threadIdx.x;      // B*128*RRR/4 = 2^22
    float4* xp = (float4*)x;
    int c = (gid >> 13) & 127;                     // RRR/4 = 8192
    int b = gid >> 20;
    int g = c >> 4;
    float mean = gstats[(layer * 32 + b * 8 + g) * 2 + 0];
    float rstd = gstats[(layer * 32 + b * 8 + g) * 2 + 1];
    float sc = scale[c] * rstd;
    float bi = bias[c] - mean * sc;
    float4 v = xp[gid];
    float a0 = v.x * sc + bi, a1 = v.y * sc + bi, a2 = v.z * sc + bi, a3 = v.w * sc + bi;
    v.x = a0 / (1.f + __expf(-a0));
    v.y = a1 / (1.f + __expf(-a1));
    v.z = a2 / (1.f + __expf(-a2));
    v.w = a3 / (1.f + __expf(-a3));
    xp[gid] = v;
}

// ---------------- kernel 8: GN2 + SiLU + transpose to [b][vox][c] ----------------
__global__ __launch_bounds__(256) void k_gn_silu_transpose(const float* __restrict__ x,
                                                           float* __restrict__ xt,
                                                           const float* __restrict__ gstats,
                                                           const float* __restrict__ scale,
                                                           const float* __restrict__ bias) {
    __shared__ float t[32][33];
    int b = blockIdx.z, ct = blockIdx.y, vt = blockIdx.x;
    int col = threadIdx.x & 31;
    int r0 = threadIdx.x >> 5;     // 0..7
    #pragma unroll
    for (int i = 0; i < 4; ++i) {
        int r = r0 + 8 * i;
        int c = ct * 32 + r;
        int g = c >> 4;
        float mean = gstats[(32 + b * 8 + g) * 2 + 0];
        float rstd = gstats[(32 + b * 8 + g) * 2 + 1];
        float v = x[((size_t)(b * 128 + c)) * RRR_ + vt * 32 + col];
        v = (v - mean) * rstd * scale[c] + bias[c];
        v = v / (1.f + __expf(-v));
        t[r][col] = v;
    }
    __syncthreads();
    #pragma unroll
    for (int i = 0; i < 4; ++i) {
        int r = r0 + 8 * i;
        int vox = vt * 32 + r;
        xt[((size_t)b * RRR_ + vox) * 128 + ct * 32 + col] = t[col][r];
    }
}

// ---------------- kernel 9: point MLP (1x1 conv), writes p_raw to d_out ----------------
__global__ __launch_bounds__(256) void k_point_mlp(const float* __restrict__ feats,
                                                   const float* __restrict__ w,
                                                   const float* __restrict__ pb,
                                                   float* __restrict__ out) {
    __shared__ float wl[64 * 132];      // [c][o], stride 132 keeps 16B alignment
    int tid = threadIdx.x;
    for (int i = tid; i < 128 * 64; i += 256) {
        int o = i >> 6, c = i & 63;
        wl[c * 132 + o] = w[i];
    }
    __syncthreads();
    int gid = blockIdx.x * 256 + tid;   // B*N
    int b = gid >> 16, n = gid & (N_ - 1);
    const float* fb = feats + (size_t)b * 64 * N_ + n;
    float acc[128];
    #pragma unroll
    for (int o = 0; o < 128; ++o) acc[o] = 0.f;
    for (int c = 0; c < 64; ++c) {
        float f = fb[(size_t)c * N_];
        const float4* wr4 = (const float4*)&wl[c * 132];
        #pragma unroll
        for (int o4 = 0; o4 < 32; ++o4) {
            float4 wv = wr4[o4];
            acc[4 * o4 + 0] = fmaf(f, wv.x, acc[4 * o4 + 0]);
            acc[4 * o4 + 1] = fmaf(f, wv.y, acc[4 * o4 + 1]);
            acc[4 * o4 + 2] = fmaf(f, wv.z, acc[4 * o4 + 2]);
            acc[4 * o4 + 3] = fmaf(f, wv.w, acc[4 * o4 + 3]);
        }
    }
    float* ob = out + (size_t)b * 128 * N_ + n;
    #pragma unroll
    for (int o = 0; o < 128; ++o) ob[(size_t)o * N_] = acc[o] + pb[o];
}

// ---------------- kernel 10: devoxelize + point GN/SiLU + add ----------------
__global__ __launch_bounds__(256) void k_devox_final(const float* __restrict__ nc,
                                                     const float* __restrict__ ht,
                                                     const float* __restrict__ gstats,
                                                     const float* __restrict__ scale,
                                                     const float* __restrict__ bias,
                                                     float* __restrict__ out) {
    __shared__ float vp[64][129];
    __shared__ int sidx[64][8];
    __shared__ float swt[64][8];
    int tid = threadIdx.x;
    int blk = blockIdx.x;               // B * N/64 = 16384
    int b = blk >> 10;
    int n0 = (blk & 1023) * 64;
    if (tid < 64) {
        int n = n0 + tid;
        float f0 = nc[(size_t)b * 3 * N_ + n];
        float f1 = nc[((size_t)b * 3 + 1) * N_ + n];
        float f2 = nc[((size_t)b * 3 + 2) * N_ + n];
        float l0 = floorf(f0), l1 = floorf(f1), l2 = floorf(f2);
        float r0 = f0 - l0, r1 = f1 - l1, r2 = f2 - l2;
        int i0 = (int)l0, i1 = (int)l1, i2 = (int)l2;
        int h0 = min(i0 + 1, 31), h1 = min(i1 + 1, 31), h2 = min(i2 + 1, 31);
        #pragma unroll
        for (int k = 0; k < 8; ++k) {
            int dx = (k >> 2) & 1, dy = (k >> 1) & 1, dz = k & 1;
            int ix = dx ? h0 : i0, iy = dy ? h1 : i1, iz = dz ? h2 : i2;
            float w = (dx ? r0 : 1.f - r0) * (dy ? r1 : 1.f - r1) * (dz ? r2 : 1.f - r2);
            sidx[tid][k] = (ix * 32 + iy) * 32 + iz;
            swt[tid][k] = w;
        }
    }
    __syncthreads();
    const float* hb = ht + (size_t)b * RRR_ * 128;
    for (int t = tid; t < 64 * 128; t += 256) {
        int c = t & 127;
        int pt = t >> 7;
        float a = 0.f;
        #pragma unroll
        for (int k = 0; k < 8; ++k)
            a = fmaf(swt[pt][k], hb[(size_t)sidx[pt][k] * 128 + c], a);
        vp[pt][c] = a;
    }
    __syncthreads();
    for (int t = tid; t < 64 * 128; t += 256) {
        int nl = t & 63;
        int c = t >> 6;
        int g = c >> 4;
        float mean = gstats[(64 + b * 8 + g) * 2 + 0];
        float rstd = gstats[(64 + b * 8 + g) * 2 + 1];
        size_t o = ((size_t)(b * 128 + c)) * N_ + n0 + nl;
        float v = (out[o] - mean) * rstd * scale[c] + bias[c];
        v = v / (1.f + __expf(-v));
        out[o] = v + vp[nl][c];
    }
}

extern "C" void kernel_launch(void* const* d_in, const int* in_sizes, int n_in,
                              void* d_out, int out_size, void* d_ws, size_t ws_size,
                              hipStream_t stream) {
    const float* coords   = (const float*)d_in[0];
    const float* features = (const float*)d_in[1];
    const float* conv1_w  = (const float*)d_in[2];
    const float* conv1_b  = (const float*)d_in[3];
    const float* gn1_s    = (const float*)d_in[4];
    const float* gn1_b    = (const float*)d_in[5];
    const float* conv2_w  = (const float*)d_in[6];
    const float* conv2_b  = (const float*)d_in[7];
    const float* gn2_s    = (const float*)d_in[8];
    const float* gn2_b    = (const float*)d_in[9];
    const float* point_w  = (const float*)d_in[10];
    const float* point_b  = (const float*)d_in[11];
    const float* pgn_s    = (const float*)d_in[12];
    const float* pgn_b    = (const float*)d_in[13];
    float* out = (float*)d_out;
    float* ws = (float*)d_ws;

    float* nc     = ws + OFF_NC;
    int*   vidx   = (int*)(ws + OFF_VIDX);
    float* cnt    = ws + OFF_CNT;
    float* grid   = ws + OFF_GRID;
    float* buf1   = ws + OFF_BUF1;
    float* buf2   = ws + OFF_BUF2;
    float* bstats = ws + OFF_BSTATS;
    float* gstats = ws + OFF_GSTATS;

    // zero the atomic accumulators (cnt + grid are contiguous)
    hipMemsetAsync(cnt, 0, (size_t)(131072 + 8388608) * sizeof(float), stream);

    k_batch_stats<<<B_, 256, 0, stream>>>(coords, bstats);
    k_point_prep<<<B_ * N_ / 256, 256, 0, stream>>>(coords, bstats, nc, vidx, cnt);
    k_scatter<<<B_ * 64 * N_ / 256, 256, 0, stream>>>(features, vidx, grid);
    k_gridmean<<<B_ * 64 * RRR_ / 256, 256, 0, stream>>>(grid, cnt);

    k_conv3d<64><<<dim3(32, 64, 4), 256, 0, stream>>>(grid, conv1_w, conv1_b, buf1);
    k_gn_stats<<<32, 256, 0, stream>>>(buf1, gstats, RRR_, 0);
    k_gn_silu<<<B_ * CO_ * RRR_ / 4 / 256, 256, 0, stream>>>(buf1, gstats, gn1_s, gn1_b, 0);

    k_conv3d<128><<<dim3(32, 64, 4), 256, 0, stream>>>(buf1, conv2_w, conv2_b, buf2);
    k_gn_stats<<<32, 256, 0, stream>>>(buf2, gstats, RRR_, 1);
    k_gn_silu_transpose<<<dim3(1024, 4, 4), 256, 0, stream>>>(buf2, buf1, gstats, gn2_s, gn2_b);

    k_point_mlp<<<B_ * N_ / 256, 256, 0, stream>>>(features, point_w, point_b, out);
    k_gn_stats<<<32, 256, 0, stream>>>(out, gstats, N_, 2);
    k_devox_final<<<B_ * N_ / 64, 256, 0, stream>>>(nc, buf1, gstats, pgn_s, pgn_b, out);
}

// Round 2
// 1401.247 us; speedup vs baseline: 8.2001x; 8.2001x over previous
//
#include <hip/hip_runtime.h>

typedef __attribute__((ext_vector_type(8))) short bf16x8;
typedef __attribute__((ext_vector_type(4))) float f32x4;
typedef __attribute__((ext_vector_type(4))) int i32x4;
typedef __attribute__((ext_vector_type(2))) int i32x2;

#define B_ 4
#define N_ 65536
#define RRR_ 32768
#define PADV_ 39304   // 34^3
#define PPLANE_ 1156  // 34*34

// ---- workspace layout (float offsets) ----
static const size_t OFF_NC     = 0;         //  [4][3][65536] f32
static const size_t OFF_VIDX   = 786432;    //  [4][65536] int
static const size_t OFF_BSTATS = 1048576;   //  [4][4] f32
static const size_t OFF_WT1    = 1048592;   //  [27][128][64] bf16
static const size_t OFF_WT2    = 1159184;   //  [27][128][128] bf16
static const size_t OFF_C2OUT  = 1380368;   //  [4][32768][128] bf16
// ---- memset region starts here ----
static const size_t OFF_CNT    = 9768976;   //  [4][32768] f32
static const size_t OFF_GSUM   = 9900048;   //  [4][32768][64] f32
static const size_t OFF_GPAD   = 18288656;  //  [4][39304][64] bf16
static const size_t OFF_ACT1   = 23319568;  //  [4][39304][128] bf16
static const size_t OFF_GSTATS = 33381392;  //  [3][4][8][2] f32
static const size_t MEMSET_FLOATS = 33381584 - 9768976;

__device__ __forceinline__ ushort f2bf(float x) {
    union { float f; unsigned u; } c; c.f = x;
    unsigned r = c.u + 0x7fffu + ((c.u >> 16) & 1u);
    return (ushort)(r >> 16);
}
__device__ __forceinline__ float bf2f(ushort h) {
    union { unsigned u; float f; } c; c.u = ((unsigned)h) << 16;
    return c.f;
}

// ---------------- per-batch coord mean + max-norm ----------------
__global__ __launch_bounds__(256) void k_batch_stats(const float* __restrict__ coords,
                                                     float* __restrict__ bstats) {
    int b = blockIdx.x;
    int tid = threadIdx.x;
    __shared__ float red[256];
    __shared__ float meansh[3];
    const float* cb = coords + (size_t)b * 3 * N_;
    float s0 = 0.f, s1 = 0.f, s2 = 0.f;
    for (int n = tid; n < N_; n += 256) {
        s0 += cb[n]; s1 += cb[N_ + n]; s2 += cb[2 * N_ + n];
    }
    float svals[3] = {s0, s1, s2};
    for (int d = 0; d < 3; ++d) {
        red[tid] = svals[d];
        __syncthreads();
        for (int o = 128; o > 0; o >>= 1) {
            if (tid < o) red[tid] += red[tid + o];
            __syncthreads();
        }
        if (tid == 0) meansh[d] = red[0] / (float)N_;
        __syncthreads();
    }
    float m0 = meansh[0], m1 = meansh[1], m2 = meansh[2];
    float mx = 0.f;
    for (int n = tid; n < N_; n += 256) {
        float x = cb[n] - m0, y = cb[N_ + n] - m1, z = cb[2 * N_ + n] - m2;
        mx = fmaxf(mx, x * x + y * y + z * z);
    }
    red[tid] = mx;
    __syncthreads();
    for (int o = 128; o > 0; o >>= 1) {
        if (tid < o) red[tid] = fmaxf(red[tid], red[tid + o]);
        __syncthreads();
    }
    if (tid == 0) {
        bstats[b * 4 + 0] = m0;
        bstats[b * 4 + 1] = m1;
        bstats[b * 4 + 2] = m2;
        bstats[b * 4 + 3] = 2.0f * sqrtf(red[0]);
    }
}

// ---------------- normalized coords, voxel idx, counts ----------------
__global__ __launch_bounds__(256) void k_point_prep(const float* __restrict__ coords,
                                                    const float* __restrict__ bstats,
                                                    float* __restrict__ nc,
                                                    int* __restrict__ vidx,
                                                    float* __restrict__ cnt) {
    int gid = blockIdx.x * 256 + threadIdx.x;
    int b = gid >> 16;
    int n = gid & (N_ - 1);
    float m[3] = {bstats[b * 4 + 0], bstats[b * 4 + 1], bstats[b * 4 + 2]};
    float den = bstats[b * 4 + 3];
    const float* cb = coords + (size_t)b * 3 * N_;
    int vi[3];
    #pragma unroll
    for (int d = 0; d < 3; ++d) {
        float cv = cb[(size_t)d * N_ + n];
        float t = (cv - m[d]) / den + 0.5f;
        t *= 32.0f;
        t = fminf(fmaxf(t, 0.0f), 31.0f);
        nc[((size_t)b * 3 + d) * N_ + n] = t;
        vi[d] = (int)rintf(t);
    }
    int flat = (vi[0] * 32 + vi[1]) * 32 + vi[2];
    vidx[(b << 16) + n] = flat;
    atomicAdd(&cnt[(b << 15) + flat], 1.0f);
}

// ---------------- scatter-add features (channels-last, LDS staged) ----------------
__global__ __launch_bounds__(256) void k_scatter_cl(const float* __restrict__ feats,
                                                    const int* __restrict__ vidx,
                                                    float* __restrict__ gsum) {
    __shared__ float lf[64 * 129];
    __shared__ int sidx[128];
    int tid = threadIdx.x;
    int b = blockIdx.y;
    int n0 = blockIdx.x * 128;
    // stage features [64ci][128pt]
    for (int i = tid; i < 64 * 128; i += 256) {
        int ci = i >> 7, pt = i & 127;
        lf[ci * 129 + pt] = feats[((size_t)(b * 64 + ci)) * N_ + n0 + pt];
    }
    if (tid < 128) sidx[tid] = vidx[(b << 16) + n0 + tid];
    __syncthreads();
    for (int i = tid; i < 64 * 128; i += 256) {
        int ci = i & 63, pt = i >> 6;
        atomicAdd(&gsum[((size_t)(b << 15) + sidx[pt]) * 64 + ci], lf[ci * 129 + pt]);
    }
}

// ---------------- sum -> mean, to padded bf16 channels-last ----------------
__global__ __launch_bounds__(256) void k_gridmean_cl(const float* __restrict__ gsum,
                                                     const float* __restrict__ cnt,
                                                     ushort* __restrict__ gpad) {
    int idx = blockIdx.x * 256 + threadIdx.x;     // 4*32768*16
    int q = idx & 15;
    int vox = (idx >> 4) & 32767;
    int b = idx >> 19;
    float c = cnt[(b << 15) + vox];
    float inv = 1.0f / fmaxf(c, 1.0f);
    float4 v = *(const float4*)(gsum + (((size_t)(b << 15) + vox) << 6) + q * 4);
    int zz = vox >> 10, yy = (vox >> 5) & 31, xx = vox & 31;
    size_t o = ((size_t)b * PADV_ + (size_t)(zz + 1) * PPLANE_ + (yy + 1) * 34 + (xx + 1)) * 64 + q * 4;
    i32x2 pk;
    ushort* u = (ushort*)&pk;
    u[0] = f2bf(v.x * inv); u[1] = f2bf(v.y * inv);
    u[2] = f2bf(v.z * inv); u[3] = f2bf(v.w * inv);
    *(i32x2*)(gpad + o) = pk;
}

// ---------------- weight transpose [co][ci][27] f32 -> [27][co][ci] bf16 ----------------
template <int CI>
__global__ __launch_bounds__(256) void k_wtrans(const float* __restrict__ w,
                                                ushort* __restrict__ wt) {
    int idx = blockIdx.x * 256 + threadIdx.x;
    if (idx >= 27 * 128 * CI) return;
    int tap = idx / (128 * CI);
    int rem = idx - tap * 128 * CI;
    int co = rem / CI;
    int ci = rem - co * CI;
    wt[idx] = f2bf(w[((size_t)co * CI + ci) * 27 + tap]);
}

// ---------------- 3^3 conv as shift-GEMM MFMA ----------------
// in: padded [b][34^3][CI] bf16 ; wt: [27][128][CI] bf16 ; out 128 co
// block: 128 positions (z fixed, 4 y-rows, 32 x) x 128 co, 4 waves
template <int CI, bool PAD_OUT>
__global__ __launch_bounds__(256, 2) void k_conv(const ushort* __restrict__ inp,
                                                 const ushort* __restrict__ wt,
                                                 const float* __restrict__ bias,
                                                 ushort* __restrict__ outp) {
    constexpr int NCHUNK = CI / 32;
    __shared__ i32x4 lds_mem[2448];            // 39168 B: [3dz][6dy][34x][32ci] bf16
    char* lds_raw = (char*)lds_mem;

    const int yq = blockIdx.x, z = blockIdx.y, b = blockIdx.z;
    const int y0 = yq * 4;
    const int tid = threadIdx.x;
    const int w = tid >> 6, l = tid & 63;
    const int lk = l >> 4;
    const int lr = l & 15;
    const int phalf = (w & 1) * 64, chalf = (w >> 1) * 64;

    const ushort* inb = inp + (size_t)b * PADV_ * CI;

    int aoff[4];
    #pragma unroll
    for (int i = 0; i < 4; ++i) {
        int pos = phalf + i * 16 + lr;
        int ly = pos >> 5, x = pos & 31;
        aoff[i] = (ly * 34 + x) * 64 + lk * 16;
    }
    size_t boff[4];
    #pragma unroll
    for (int n = 0; n < 4; ++n)
        boff[n] = ((size_t)(chalf + n * 16 + lr) * CI) * 2 + lk * 16;
    const char* wtb = (const char*)wt;

    f32x4 acc[4][4];
    #pragma unroll
    for (int i = 0; i < 4; ++i)
        #pragma unroll
        for (int n = 0; n < 4; ++n)
            acc[i][n] = (f32x4){0.f, 0.f, 0.f, 0.f};

    bf16x8 bfrag[4], bnext[4];

    for (int chunk = 0; chunk < NCHUNK; ++chunk) {
        __syncthreads();
        {   // stage input slab: 18 rows x 34 x x 4 b128
            const ushort* src = inb + chunk * 32;
            for (int idx = tid; idx < 2448; idx += 256) {
                int t4 = idx & 3;
                int r = idx >> 2;
                int x = r % 34;
                int row = r / 34;                // 0..17
                int dz = row / 6, dy = row - dz * 6;
                i32x4 v = *(const i32x4*)(src + ((size_t)((z + dz) * PPLANE_ + (y0 + dy) * 34 + x)) * CI + t4 * 8);
                lds_mem[idx] = v;
            }
        }
        {   // first tap's B fragments
            const char* wp = wtb + ((size_t)(chunk * 32)) * 2;
            #pragma unroll
            for (int n = 0; n < 4; ++n) bfrag[n] = *(const bf16x8*)(wp + boff[n]);
        }
        __syncthreads();
        for (int tap = 0; tap < 27; ++tap) {
            if (tap < 26) {
                const char* wp = wtb + ((size_t)((tap + 1) * 128 * CI + chunk * 32)) * 2;
                #pragma unroll
                for (int n = 0; n < 4; ++n) bnext[n] = *(const bf16x8*)(wp + boff[n]);
            }
            int fz = tap / 9, r9 = tap - fz * 9;
            int fy = r9 / 3, fx = r9 - fy * 3;
            int doff = ((fz * 6 + fy) * 34 + fx) * 64;
            bf16x8 afrag[4];
            #pragma unroll
            for (int i = 0; i < 4; ++i)
                afrag[i] = *(const bf16x8*)(lds_raw + aoff[i] + doff);
            #pragma unroll
            for (int i = 0; i < 4; ++i)
                #pragma unroll
                for (int n = 0; n < 4; ++n)
                    acc[i][n] = __builtin_amdgcn_mfma_f32_16x16x32_bf16(afrag[i], bfrag[n], acc[i][n], 0, 0, 0);
            #pragma unroll
            for (int n = 0; n < 4; ++n) bfrag[n] = bnext[n];
        }
    }

    // epilogue: acc -> LDS tile [128pos][128co] bf16, then coalesced dump
    __syncthreads();
    ushort* outs = (ushort*)lds_mem;
    float bb[4];
    #pragma unroll
    for (int n = 0; n < 4; ++n) bb[n] = bias[chalf + n * 16 + lr];
    #pragma unroll
    for (int i = 0; i < 4; ++i) {
        int posb = phalf + i * 16 + lk * 4;
        #pragma unroll
        for (int n = 0; n < 4; ++n) {
            int co = chalf + n * 16 + lr;
            #pragma unroll
            for (int r = 0; r < 4; ++r)
                outs[(posb + r) * 128 + co] = f2bf(acc[i][n][r] + bb[n]);
        }
    }
    __syncthreads();
    for (int idx = tid; idx < 2048; idx += 256) {
        int pos = idx >> 4, c8 = idx & 15;
        int ly = pos >> 5, x = pos & 31;
        size_t g;
        if (PAD_OUT)
            g = ((size_t)b * PADV_ + (size_t)(z + 1) * PPLANE_ + (y0 + ly + 1) * 34 + (x + 1)) * 128 + c8 * 8;
        else
            g = ((size_t)b * RRR_ + z * 1024 + (y0 + ly) * 32 + x) * 128 + c8 * 8;
        *(i32x4*)(outp + g) = *((i32x4*)lds_raw + idx);
    }
}

// ---------------- GN stats over channels-last bf16 (raw sum/ss via atomics) ----------------
__global__ __launch_bounds__(256) void k_gn_stats_cl(const ushort* __restrict__ x,
                                                     float* __restrict__ gstats,
                                                     int nvox, int layer) {
    int b = blockIdx.y;
    int tid = threadIdx.x;
    int total = nvox * 16;
    float s = 0.f, ss = 0.f;
    const ushort* xb = x + (size_t)b * nvox * 128;
    for (int idx = blockIdx.x * 256 + tid; idx < total; idx += 64 * 256) {
        i32x4 raw = *(const i32x4*)(xb + (size_t)idx * 8);
        ushort* u = (ushort*)&raw;
        #pragma unroll
        for (int j = 0; j < 8; ++j) { float v = bf2f(u[j]); s += v; ss += v * v; }
    }
    s  += __shfl_xor(s, 1);  ss += __shfl_xor(ss, 1);
    s  += __shfl_xor(s, 16); ss += __shfl_xor(ss, 16);
    s  += __shfl_xor(s, 32); ss += __shfl_xor(ss, 32);
    int l = tid & 63;
    if (l < 16 && (l & 1) == 0) {
        int g = l >> 1;
        atomicAdd(&gstats[(layer * 32 + b * 8 + g) * 2 + 0], s);
        atomicAdd(&gstats[(layer * 32 + b * 8 + g) * 2 + 1], ss);
    }
}

// ---------------- GN + SiLU apply (channels-last bf16, padded or flat) ----------------
template <bool PAD>
__global__ __launch_bounds__(256) void k_gn_apply(ushort* __restrict__ x,
                                                  const float* __restrict__ gstats,
                                                  const float* __restrict__ sc,
                                                  const float* __restrict__ bi,
                                                  int layer, float invc) {
    int idx = blockIdx.x * 256 + threadIdx.x;   // 4*32768*16
    int c8 = idx & 15;
    int vox = (idx >> 4) & 32767;
    int b = idx >> 19;
    size_t base;
    if (PAD) {
        int zz = vox >> 10, yy = (vox >> 5) & 31, xx = vox & 31;
        base = ((size_t)b * PADV_ + (size_t)(zz + 1) * PPLANE_ + (yy + 1) * 34 + (xx + 1)) * 128 + c8 * 8;
    } else {
        base = ((size_t)b * RRR_ + vox) * 128 + c8 * 8;
    }
    int g = c8 >> 1;
    float sum = gstats[(layer * 32 + b * 8 + g) * 2 + 0];
    float ssq = gstats[(layer * 32 + b * 8 + g) * 2 + 1];
    float mean = sum * invc;
    float var = ssq * invc - mean * mean;
    float rstd = rsqrtf(var + 1e-5f);
    i32x4 raw = *(i32x4*)(x + base);
    ushort* u = (ushort*)&raw;
    #pragma unroll
    for (int j = 0; j < 8; ++j) {
        int co = c8 * 8 + j;
        float v = bf2f(u[j]);
        v = (v - mean) * rstd * sc[co] + bi[co];
        v = v / (1.f + __expf(-v));
        u[j] = f2bf(v);
    }
    *(i32x4*)(x + base) = raw;
}

// ---------------- point MLP (1x1 conv), writes p_raw to d_out ----------------
__global__ __launch_bounds__(256) void k_point_mlp(const float* __restrict__ feats,
                                                   const float* __restrict__ w,
                                                   const float* __restrict__ pb,
                                                   float* __restrict__ out) {
    __shared__ float wl[64 * 132];
    int tid = threadIdx.x;
    for (int i = tid; i < 128 * 64; i += 256) {
        int o = i >> 6, c = i & 63;
        wl[c * 132 + o] = w[i];
    }
    __syncthreads();
    int gid = blockIdx.x * 256 + tid;
    int b = gid >> 16, n = gid & (N_ - 1);
    const float* fb = feats + (size_t)b * 64 * N_ + n;
    float acc[128];
    #pragma unroll
    for (int o = 0; o < 128; ++o) acc[o] = 0.f;
    for (int c = 0; c < 64; ++c) {
        float f = fb[(size_t)c * N_];
        const float4* wr4 = (const float4*)&wl[c * 132];
        #pragma unroll
        for (int o4 = 0; o4 < 32; ++o4) {
            float4 wv = wr4[o4];
            acc[4 * o4 + 0] = fmaf(f, wv.x, acc[4 * o4 + 0]);
            acc[4 * o4 + 1] = fmaf(f, wv.y, acc[4 * o4 + 1]);
            acc[4 * o4 + 2] = fmaf(f, wv.z, acc[4 * o4 + 2]);
            acc[4 * o4 + 3] = fmaf(f, wv.w, acc[4 * o4 + 3]);
        }
    }
    float* ob = out + (size_t)b * 128 * N_ + n;
    #pragma unroll
    for (int o = 0; o < 128; ++o) ob[(size_t)o * N_] = acc[o] + pb[o];
}

// ---------------- GN stats, channel-major fp32 (point branch) -> mean/rstd ----------------
__global__ __launch_bounds__(256) void k_gn_stats(const float* __restrict__ x,
                                                  float* __restrict__ gstats,
                                                  int spatial, int layer) {
    int bg = blockIdx.x;
    int tid = threadIdx.x;
    const float4* base = (const float4*)(x + (size_t)bg * 16 * spatial);
    int cnt4 = 16 * spatial / 4;
    float s = 0.f, ss = 0.f;
    for (int i = tid; i < cnt4; i += 256) {
        float4 v = base[i];
        s += (v.x + v.y) + (v.z + v.w);
        ss += (v.x * v.x + v.y * v.y) + (v.z * v.z + v.w * v.w);
    }
    __shared__ float r1[256], r2[256];
    r1[tid] = s; r2[tid] = ss;
    __syncthreads();
    for (int o = 128; o > 0; o >>= 1) {
        if (tid < o) { r1[tid] += r1[tid + o]; r2[tid] += r2[tid + o]; }
        __syncthreads();
    }
    if (tid == 0) {
        float count = (float)(16 * spatial);
        float mean = r1[0] / count;
        float var = r2[0] / count - mean * mean;
        gstats[(layer * 32 + bg) * 2 + 0] = mean;
        gstats[(layer * 32 + bg) * 2 + 1] = rsqrtf(var + 1e-5f);
    }
}

// ---------------- devoxelize + point GN/SiLU + add ----------------
__global__ __launch_bounds__(256) void k_devox_final(const float* __restrict__ nc,
                                                     const ushort* __restrict__ ht,
                                                     const float* __restrict__ gstats,
                                                     const float* __restrict__ scale,
                                                     const float* __restrict__ bias,
                                                     float* __restrict__ out) {
    __shared__ float vp[64][129];
    __shared__ int sidx[64][8];
    __shared__ float swt[64][8];
    int tid = threadIdx.x;
    int blk = blockIdx.x;               // B * N/64 = 4096
    int b = blk >> 10;
    int n0 = (blk & 1023) * 64;
    if (tid < 64) {
        int n = n0 + tid;
        float f0 = nc[(size_t)b * 3 * N_ + n];
        float f1 = nc[((size_t)b * 3 + 1) * N_ + n];
        float f2 = nc[((size_t)b * 3 + 2) * N_ + n];
        float l0 = floorf(f0), l1 = floorf(f1), l2 = floorf(f2);
        float r0 = f0 - l0, r1 = f1 - l1, r2 = f2 - l2;
        int i0 = (int)l0, i1 = (int)l1, i2 = (int)l2;
        int h0 = min(i0 + 1, 31), h1 = min(i1 + 1, 31), h2 = min(i2 + 1, 31);
        #pragma unroll
        for (int k = 0; k < 8; ++k) {
            int dx = (k >> 2) & 1, dy = (k >> 1) & 1, dz = k & 1;
            int ix = dx ? h0 : i0, iy = dy ? h1 : i1, iz = dz ? h2 : i2;
            float w = (dx ? r0 : 1.f - r0) * (dy ? r1 : 1.f - r1) * (dz ? r2 : 1.f - r2);
            sidx[tid][k] = (ix * 32 + iy) * 32 + iz;
            swt[tid][k] = w;
        }
    }
    __syncthreads();
    const ushort* hb = ht + (size_t)b * RRR_ * 128;
    for (int t = tid; t < 64 * 128; t += 256) {
        int c = t & 127;
        int pt = t >> 7;
        float a = 0.f;
        #pragma unroll
        for (int k = 0; k < 8; ++k)
            a = fmaf(swt[pt][k], bf2f(hb[(size_t)sidx[pt][k] * 128 + c]), a);
        vp[pt][c] = a;
    }
    __syncthreads();
    for (int t = tid; t < 64 * 128; t += 256) {
        int nl = t & 63;
        int c = t >> 6;
        int g = c >> 4;
        float mean = gstats[(64 + b * 8 + g) * 2 + 0];
        float rstd = gstats[(64 + b * 8 + g) * 2 + 1];
        size_t o = ((size_t)(b * 128 + c)) * N_ + n0 + nl;
        float v = (out[o] - mean) * rstd * scale[c] + bias[c];
        v = v / (1.f + __expf(-v));
        out[o] = v + vp[nl][c];
    }
}

extern "C" void kernel_launch(void* const* d_in, const int* in_sizes, int n_in,
                              void* d_out, int out_size, void* d_ws, size_t ws_size,
                              hipStream_t stream) {
    const float* coords   = (const float*)d_in[0];
    const float* features = (const float*)d_in[1];
    const float* conv1_w  = (const float*)d_in[2];
    const float* conv1_b  = (const float*)d_in[3];
    const float* gn1_s    = (const float*)d_in[4];
    const float* gn1_b    = (const float*)d_in[5];
    const float* conv2_w  = (const float*)d_in[6];
    const float* conv2_b  = (const float*)d_in[7];
    const float* gn2_s    = (const float*)d_in[8];
    const float* gn2_b    = (const float*)d_in[9];
    const float* point_w  = (const float*)d_in[10];
    const float* point_b  = (const float*)d_in[11];
    const float* pgn_s    = (const float*)d_in[12];
    const float* pgn_b    = (const float*)d_in[13];
    float* out = (float*)d_out;
    float* ws = (float*)d_ws;

    float*  nc     = ws + OFF_NC;
    int*    vidx   = (int*)(ws + OFF_VIDX);
    float*  bstats = ws + OFF_BSTATS;
    ushort* wt1    = (ushort*)(ws + OFF_WT1);
    ushort* wt2    = (ushort*)(ws + OFF_WT2);
    ushort* c2out  = (ushort*)(ws + OFF_C2OUT);
    float*  cnt    = ws + OFF_CNT;
    float*  gsum   = ws + OFF_GSUM;
    ushort* gpad   = (ushort*)(ws + OFF_GPAD);
    ushort* act1   = (ushort*)(ws + OFF_ACT1);
    float*  gstats = ws + OFF_GSTATS;

    const float invc = 1.0f / (float)(RRR_ * 16);

    hipMemsetAsync(cnt, 0, MEMSET_FLOATS * sizeof(float), stream);

    k_batch_stats<<<B_, 256, 0, stream>>>(coords, bstats);
    k_point_prep<<<B_ * N_ / 256, 256, 0, stream>>>(coords, bstats, nc, vidx, cnt);
    k_scatter_cl<<<dim3(N_ / 128, B_), 256, 0, stream>>>(features, vidx, gsum);
    k_gridmean_cl<<<B_ * RRR_ * 16 / 256, 256, 0, stream>>>(gsum, cnt, gpad);

    k_wtrans<64><<<(27 * 128 * 64 + 255) / 256, 256, 0, stream>>>(conv1_w, wt1);
    k_wtrans<128><<<(27 * 128 * 128 + 255) / 256, 256, 0, stream>>>(conv2_w, wt2);

    k_conv<64, true><<<dim3(8, 32, B_), 256, 0, stream>>>(gpad, wt1, conv1_b, act1);
    k_gn_stats_cl<<<dim3(64, B_), 256, 0, stream>>>(act1, gstats, PADV_, 0);
    k_gn_apply<true><<<B_ * RRR_ * 16 / 256, 256, 0, stream>>>(act1, gstats, gn1_s, gn1_b, 0, invc);

    k_conv<128, false><<<dim3(8, 32, B_), 256, 0, stream>>>(act1, wt2, conv2_b, c2out);
    k_gn_stats_cl<<<dim3(64, B_), 256, 0, stream>>>(c2out, gstats, RRR_, 1);
    k_gn_apply<false><<<B_ * RRR_ * 16 / 256, 256, 0, stream>>>(c2out, gstats, gn2_s, gn2_b, 1, invc);

    k_point_mlp<<<B_ * N_ / 256, 256, 0, stream>>>(features, point_w, point_b, out);
    k_gn_stats<<<32, 256, 0, stream>>>(out, gstats, N_, 2);
    k_devox_final<<<B_ * N_ / 64, 256, 0, stream>>>(nc, c2out, gstats, pgn_s, pgn_b, out);
}

// Round 3
// 1395.875 us; speedup vs baseline: 8.2316x; 1.0038x over previous
//
#include <hip/hip_runtime.h>

typedef __attribute__((ext_vector_type(8))) short bf16x8;
typedef __attribute__((ext_vector_type(4))) float f32x4;
typedef __attribute__((ext_vector_type(4))) int i32x4;
typedef __attribute__((ext_vector_type(2))) int i32x2;

#define B_ 4
#define N_ 65536
#define RRR_ 32768
#define PADV_ 39304   // 34^3
#define PPLANE_ 1156  // 34*34

// ---- workspace layout (float offsets) ----
static const size_t OFF_NC     = 0;         //  [4][3][65536] f32
static const size_t OFF_VIDX   = 786432;    //  [4][65536] int
static const size_t OFF_WT1    = 1048576;   //  [27][128][64] bf16
static const size_t OFF_WT2    = 1159168;   //  [27][128][128] bf16
static const size_t OFF_C2OUT  = 1380352;   //  [4][32768][128] bf16
// ---- memset region starts here ----
static const size_t OFF_CNT    = 9768960;   //  [4][32768] f32
static const size_t OFF_GSUM   = 9900032;   //  [4][32768][64] f32
static const size_t OFF_GPAD   = 18288640;  //  [4][39304][64] bf16
static const size_t OFF_ACT1   = 23319552;  //  [4][39304][128] bf16
static const size_t OFF_GSTATS = 33381376;  //  [3][4][8][2] f32 raw sum/ssq
static const size_t OFF_BSTATS = 33381568;  //  [4][4] f32 (sum x3, maxbits)
static const size_t MEMSET_FLOATS = 33381584 - 9768960;

__device__ __forceinline__ ushort f2bf(float x) {
    union { float f; unsigned u; } c; c.f = x;
    unsigned r = c.u + 0x7fffu + ((c.u >> 16) & 1u);
    return (ushort)(r >> 16);
}
__device__ __forceinline__ float bf2f(ushort h) {
    union { unsigned u; float f; } c; c.u = ((unsigned)h) << 16;
    return c.f;
}

// ---------------- coord partial sums ----------------
__global__ __launch_bounds__(256) void k_coord_sum(const float* __restrict__ coords,
                                                   float* __restrict__ bstats) {
    int b = blockIdx.y;
    int tid = threadIdx.x;
    const float* cb = coords + (size_t)b * 3 * N_;
    float s0 = 0.f, s1 = 0.f, s2 = 0.f;
    for (int n = blockIdx.x * 256 + tid; n < N_; n += 64 * 256) {
        s0 += cb[n]; s1 += cb[N_ + n]; s2 += cb[2 * N_ + n];
    }
    #pragma unroll
    for (int off = 1; off < 64; off <<= 1) {
        s0 += __shfl_xor(s0, off);
        s1 += __shfl_xor(s1, off);
        s2 += __shfl_xor(s2, off);
    }
    if ((tid & 63) == 0) {
        atomicAdd(&bstats[b * 4 + 0], s0);
        atomicAdd(&bstats[b * 4 + 1], s1);
        atomicAdd(&bstats[b * 4 + 2], s2);
    }
}

// ---------------- coord max-norm (after sums) ----------------
__global__ __launch_bounds__(256) void k_coord_max(const float* __restrict__ coords,
                                                   float* __restrict__ bstats) {
    int b = blockIdx.y;
    int tid = threadIdx.x;
    const float invN = 1.0f / (float)N_;
    float m0 = bstats[b * 4 + 0] * invN;
    float m1 = bstats[b * 4 + 1] * invN;
    float m2 = bstats[b * 4 + 2] * invN;
    const float* cb = coords + (size_t)b * 3 * N_;
    float mx = 0.f;
    for (int n = blockIdx.x * 256 + tid; n < N_; n += 64 * 256) {
        float x = cb[n] - m0, y = cb[N_ + n] - m1, z = cb[2 * N_ + n] - m2;
        mx = fmaxf(mx, x * x + y * y + z * z);
    }
    #pragma unroll
    for (int off = 1; off < 64; off <<= 1)
        mx = fmaxf(mx, __shfl_xor(mx, off));
    if ((tid & 63) == 0)
        atomicMax((int*)&bstats[b * 4 + 3], __float_as_int(mx));
}

// ---------------- normalized coords, voxel idx, counts ----------------
__global__ __launch_bounds__(256) void k_point_prep(const float* __restrict__ coords,
                                                    const float* __restrict__ bstats,
                                                    float* __restrict__ nc,
                                                    int* __restrict__ vidx,
                                                    float* __restrict__ cnt) {
    int gid = blockIdx.x * 256 + threadIdx.x;
    int b = gid >> 16;
    int n = gid & (N_ - 1);
    const float invN = 1.0f / (float)N_;
    float m[3] = {bstats[b * 4 + 0] * invN, bstats[b * 4 + 1] * invN, bstats[b * 4 + 2] * invN};
    float den = 2.0f * sqrtf(__int_as_float(((const int*)bstats)[b * 4 + 3]));
    const float* cb = coords + (size_t)b * 3 * N_;
    int vi[3];
    #pragma unroll
    for (int d = 0; d < 3; ++d) {
        float cv = cb[(size_t)d * N_ + n];
        float t = (cv - m[d]) / den + 0.5f;
        t *= 32.0f;
        t = fminf(fmaxf(t, 0.0f), 31.0f);
        nc[((size_t)b * 3 + d) * N_ + n] = t;
        vi[d] = (int)rintf(t);
    }
    int flat = (vi[0] * 32 + vi[1]) * 32 + vi[2];
    vidx[(b << 16) + n] = flat;
    atomicAdd(&cnt[(b << 15) + flat], 1.0f);
}

// ---------------- scatter-add features (channels-last, LDS staged) ----------------
__global__ __launch_bounds__(256) void k_scatter_cl(const float* __restrict__ feats,
                                                    const int* __restrict__ vidx,
                                                    float* __restrict__ gsum) {
    __shared__ float lf[64 * 129];
    __shared__ int sidx[128];
    int tid = threadIdx.x;
    int b = blockIdx.y;
    int n0 = blockIdx.x * 128;
    for (int i = tid; i < 64 * 128; i += 256) {
        int ci = i >> 7, pt = i & 127;
        lf[ci * 129 + pt] = feats[((size_t)(b * 64 + ci)) * N_ + n0 + pt];
    }
    if (tid < 128) sidx[tid] = vidx[(b << 16) + n0 + tid];
    __syncthreads();
    for (int i = tid; i < 64 * 128; i += 256) {
        int ci = i & 63, pt = i >> 6;
        atomicAdd(&gsum[((size_t)(b << 15) + sidx[pt]) * 64 + ci], lf[ci * 129 + pt]);
    }
}

// ---------------- sum -> mean, to padded bf16 channels-last ----------------
__global__ __launch_bounds__(256) void k_gridmean_cl(const float* __restrict__ gsum,
                                                     const float* __restrict__ cnt,
                                                     ushort* __restrict__ gpad) {
    int idx = blockIdx.x * 256 + threadIdx.x;     // 4*32768*16
    int q = idx & 15;
    int vox = (idx >> 4) & 32767;
    int b = idx >> 19;
    float c = cnt[(b << 15) + vox];
    float inv = 1.0f / fmaxf(c, 1.0f);
    float4 v = *(const float4*)(gsum + (((size_t)(b << 15) + vox) << 6) + q * 4);
    int zz = vox >> 10, yy = (vox >> 5) & 31, xx = vox & 31;
    size_t o = ((size_t)b * PADV_ + (size_t)(zz + 1) * PPLANE_ + (yy + 1) * 34 + (xx + 1)) * 64 + q * 4;
    i32x2 pk;
    ushort* u = (ushort*)&pk;
    u[0] = f2bf(v.x * inv); u[1] = f2bf(v.y * inv);
    u[2] = f2bf(v.z * inv); u[3] = f2bf(v.w * inv);
    *(i32x2*)(gpad + o) = pk;
}

// ---------------- weight transpose [co][ci][27] f32 -> [27][co][ci] bf16 ----------------
template <int CI>
__global__ __launch_bounds__(256) void k_wtrans(const float* __restrict__ w,
                                                ushort* __restrict__ wt) {
    int idx = blockIdx.x * 256 + threadIdx.x;
    if (idx >= 27 * 128 * CI) return;
    int tap = idx / (128 * CI);
    int rem = idx - tap * 128 * CI;
    int co = rem / CI;
    int ci = rem - co * CI;
    wt[idx] = f2bf(w[((size_t)co * CI + ci) * 27 + tap]);
}

// ---------------- 3^3 conv as shift-GEMM MFMA, fused GN-stats accumulation ----------------
template <int CI, bool PAD_OUT>
__global__ __launch_bounds__(256, 2) void k_conv(const ushort* __restrict__ inp,
                                                 const ushort* __restrict__ wt,
                                                 const float* __restrict__ bias,
                                                 ushort* __restrict__ outp,
                                                 float* __restrict__ gstats,
                                                 int layer) {
    constexpr int NCHUNK = CI / 32;
    __shared__ i32x4 lds_mem[2448];            // 39168 B: [3dz][6dy][34x][32ci] bf16
    char* lds_raw = (char*)lds_mem;

    const int yq = blockIdx.x, z = blockIdx.y, b = blockIdx.z;
    const int y0 = yq * 4;
    const int tid = threadIdx.x;
    const int w = tid >> 6, l = tid & 63;
    const int lk = l >> 4;
    const int lr = l & 15;
    const int phalf = (w & 1) * 64, chalf = (w >> 1) * 64;

    const ushort* inb = inp + (size_t)b * PADV_ * CI;

    int aoff[4];
    #pragma unroll
    for (int i = 0; i < 4; ++i) {
        int pos = phalf + i * 16 + lr;
        int ly = pos >> 5, x = pos & 31;
        aoff[i] = (ly * 34 + x) * 64 + lk * 16;
    }
    size_t boff[4];
    #pragma unroll
    for (int n = 0; n < 4; ++n)
        boff[n] = ((size_t)(chalf + n * 16 + lr) * CI) * 2 + lk * 16;
    const char* wtb = (const char*)wt;

    f32x4 acc[4][4];
    #pragma unroll
    for (int i = 0; i < 4; ++i)
        #pragma unroll
        for (int n = 0; n < 4; ++n)
            acc[i][n] = (f32x4){0.f, 0.f, 0.f, 0.f};

    bf16x8 bfrag[4], bnext[4];

    for (int chunk = 0; chunk < NCHUNK; ++chunk) {
        __syncthreads();
        {
            const ushort* src = inb + chunk * 32;
            for (int idx = tid; idx < 2448; idx += 256) {
                int t4 = idx & 3;
                int r = idx >> 2;
                int x = r % 34;
                int row = r / 34;                // 0..17
                int dz = row / 6, dy = row - dz * 6;
                i32x4 v = *(const i32x4*)(src + ((size_t)((z + dz) * PPLANE_ + (y0 + dy) * 34 + x)) * CI + t4 * 8);
                lds_mem[idx] = v;
            }
        }
        {
            const char* wp = wtb + ((size_t)(chunk * 32)) * 2;
            #pragma unroll
            for (int n = 0; n < 4; ++n) bfrag[n] = *(const bf16x8*)(wp + boff[n]);
        }
        __syncthreads();
        for (int tap = 0; tap < 27; ++tap) {
            if (tap < 26) {
                const char* wp = wtb + ((size_t)((tap + 1) * 128 * CI + chunk * 32)) * 2;
                #pragma unroll
                for (int n = 0; n < 4; ++n) bnext[n] = *(const bf16x8*)(wp + boff[n]);
            }
            int fz = tap / 9, r9 = tap - fz * 9;
            int fy = r9 / 3, fx = r9 - fy * 3;
            int doff = ((fz * 6 + fy) * 34 + fx) * 64;
            bf16x8 afrag[4];
            #pragma unroll
            for (int i = 0; i < 4; ++i)
                afrag[i] = *(const bf16x8*)(lds_raw + aoff[i] + doff);
            #pragma unroll
            for (int i = 0; i < 4; ++i)
                #pragma unroll
                for (int n = 0; n < 4; ++n)
                    acc[i][n] = __builtin_amdgcn_mfma_f32_16x16x32_bf16(afrag[i], bfrag[n], acc[i][n], 0, 0, 0);
            #pragma unroll
            for (int n = 0; n < 4; ++n) bfrag[n] = bnext[n];
        }
    }

    // epilogue: bias add + fused GN stats + bf16 pack via LDS + coalesced dump
    __syncthreads();
    ushort* outs = (ushort*)lds_mem;
    float bb[4];
    #pragma unroll
    for (int n = 0; n < 4; ++n) bb[n] = bias[chalf + n * 16 + lr];
    float sg[4] = {0.f, 0.f, 0.f, 0.f}, sq[4] = {0.f, 0.f, 0.f, 0.f};
    #pragma unroll
    for (int i = 0; i < 4; ++i) {
        int posb = phalf + i * 16 + lk * 4;
        #pragma unroll
        for (int n = 0; n < 4; ++n) {
            int co = chalf + n * 16 + lr;
            #pragma unroll
            for (int r = 0; r < 4; ++r) {
                float v = acc[i][n][r] + bb[n];
                sg[n] += v; sq[n] += v * v;
                outs[(posb + r) * 128 + co] = f2bf(v);
            }
        }
    }
    #pragma unroll
    for (int off = 1; off < 64; off <<= 1) {
        #pragma unroll
        for (int n = 0; n < 4; ++n) {
            sg[n] += __shfl_xor(sg[n], off);
            sq[n] += __shfl_xor(sq[n], off);
        }
    }
    if (l == 0) {
        int gbase = layer * 32 + b * 8 + (chalf >> 4);
        #pragma unroll
        for (int n = 0; n < 4; ++n) {
            atomicAdd(&gstats[(gbase + n) * 2 + 0], sg[n]);
            atomicAdd(&gstats[(gbase + n) * 2 + 1], sq[n]);
        }
    }
    __syncthreads();
    for (int idx = tid; idx < 2048; idx += 256) {
        int pos = idx >> 4, c8 = idx & 15;
        int ly = pos >> 5, x = pos & 31;
        size_t g;
        if (PAD_OUT)
            g = ((size_t)b * PADV_ + (size_t)(z + 1) * PPLANE_ + (y0 + ly + 1) * 34 + (x + 1)) * 128 + c8 * 8;
        else
            g = ((size_t)b * RRR_ + z * 1024 + (y0 + ly) * 32 + x) * 128 + c8 * 8;
        *(i32x4*)(outp + g) = *((i32x4*)lds_raw + idx);
    }
}

// ---------------- GN + SiLU apply (channels-last bf16, padded or flat) ----------------
template <bool PAD>
__global__ __launch_bounds__(256) void k_gn_apply(ushort* __restrict__ x,
                                                  const float* __restrict__ gstats,
                                                  const float* __restrict__ sc,
                                                  const float* __restrict__ bi,
                                                  int layer, float invc) {
    int idx = blockIdx.x * 256 + threadIdx.x;   // 4*32768*16
    int c8 = idx & 15;
    int vox = (idx >> 4) & 32767;
    int b = idx >> 19;
    size_t base;
    if (PAD) {
        int zz = vox >> 10, yy = (vox >> 5) & 31, xx = vox & 31;
        base = ((size_t)b * PADV_ + (size_t)(zz + 1) * PPLANE_ + (yy + 1) * 34 + (xx + 1)) * 128 + c8 * 8;
    } else {
        base = ((size_t)b * RRR_ + vox) * 128 + c8 * 8;
    }
    int g = c8 >> 1;
    float sum = gstats[(layer * 32 + b * 8 + g) * 2 + 0];
    float ssq = gstats[(layer * 32 + b * 8 + g) * 2 + 1];
    float mean = sum * invc;
    float var = ssq * invc - mean * mean;
    float rstd = rsqrtf(var + 1e-5f);
    i32x4 raw = *(i32x4*)(x + base);
    ushort* u = (ushort*)&raw;
    #pragma unroll
    for (int j = 0; j < 8; ++j) {
        int co = c8 * 8 + j;
        float v = bf2f(u[j]);
        v = (v - mean) * rstd * sc[co] + bi[co];
        v = v / (1.f + __expf(-v));
        u[j] = f2bf(v);
    }
    *(i32x4*)(x + base) = raw;
}

// ---------------- point MLP (1x1 conv) + fused GN stats ----------------
__global__ __launch_bounds__(256) void k_point_mlp(const float* __restrict__ feats,
                                                   const float* __restrict__ w,
                                                   const float* __restrict__ pb,
                                                   float* __restrict__ out,
                                                   float* __restrict__ gstats) {
    __shared__ float wl[64 * 132];
    __shared__ float sred[4][16];
    int tid = threadIdx.x;
    for (int i = tid; i < 128 * 64; i += 256) {
        int o = i >> 6, c = i & 63;
        wl[c * 132 + o] = w[i];
    }
    __syncthreads();
    int gid = blockIdx.x * 256 + tid;
    int b = gid >> 16, n = gid & (N_ - 1);
    const float* fb = feats + (size_t)b * 64 * N_ + n;
    float acc[128];
    #pragma unroll
    for (int o = 0; o < 128; ++o) acc[o] = 0.f;
    for (int c = 0; c < 64; ++c) {
        float f = fb[(size_t)c * N_];
        const float4* wr4 = (const float4*)&wl[c * 132];
        #pragma unroll
        for (int o4 = 0; o4 < 32; ++o4) {
            float4 wv = wr4[o4];
            acc[4 * o4 + 0] = fmaf(f, wv.x, acc[4 * o4 + 0]);
            acc[4 * o4 + 1] = fmaf(f, wv.y, acc[4 * o4 + 1]);
            acc[4 * o4 + 2] = fmaf(f, wv.z, acc[4 * o4 + 2]);
            acc[4 * o4 + 3] = fmaf(f, wv.w, acc[4 * o4 + 3]);
        }
    }
    float* ob = out + (size_t)b * 128 * N_ + n;
    float sg[8] = {0.f}, sq[8] = {0.f};
    #pragma unroll
    for (int o = 0; o < 128; ++o) {
        float v = acc[o] + pb[o];
        ob[(size_t)o * N_] = v;
        sg[o >> 4] += v;
        sq[o >> 4] += v * v;
    }
    #pragma unroll
    for (int off = 1; off < 64; off <<= 1) {
        #pragma unroll
        for (int g = 0; g < 8; ++g) {
            sg[g] += __shfl_xor(sg[g], off);
            sq[g] += __shfl_xor(sq[g], off);
        }
    }
    int wv = tid >> 6, l = tid & 63;
    if (l == 0) {
        #pragma unroll
        for (int g = 0; g < 8; ++g) { sred[wv][g] = sg[g]; sred[wv][8 + g] = sq[g]; }
    }
    __syncthreads();
    if (tid < 16) {
        float v = sred[0][tid] + sred[1][tid] + sred[2][tid] + sred[3][tid];
        int g = tid & 7, part = tid >> 3;
        atomicAdd(&gstats[(64 + b * 8 + g) * 2 + part], v);
    }
}

// ---------------- devoxelize + point GN/SiLU + add ----------------
__global__ __launch_bounds__(256) void k_devox_final(const float* __restrict__ nc,
                                                     const ushort* __restrict__ ht,
                                                     const float* __restrict__ gstats,
                                                     const float* __restrict__ scale,
                                                     const float* __restrict__ bias,
                                                     float* __restrict__ out) {
    __shared__ float vp[64][129];
    __shared__ int sidx[64][8];
    __shared__ float swt[64][8];
    int tid = threadIdx.x;
    int blk = blockIdx.x;               // B * N/64 = 4096
    int b = blk >> 10;
    int n0 = (blk & 1023) * 64;
    if (tid < 64) {
        int n = n0 + tid;
        float f0 = nc[(size_t)b * 3 * N_ + n];
        float f1 = nc[((size_t)b * 3 + 1) * N_ + n];
        float f2 = nc[((size_t)b * 3 + 2) * N_ + n];
        float l0 = floorf(f0), l1 = floorf(f1), l2 = floorf(f2);
        float r0 = f0 - l0, r1 = f1 - l1, r2 = f2 - l2;
        int i0 = (int)l0, i1 = (int)l1, i2 = (int)l2;
        int h0 = min(i0 + 1, 31), h1 = min(i1 + 1, 31), h2 = min(i2 + 1, 31);
        #pragma unroll
        for (int k = 0; k < 8; ++k) {
            int dx = (k >> 2) & 1, dy = (k >> 1) & 1, dz = k & 1;
            int ix = dx ? h0 : i0, iy = dy ? h1 : i1, iz = dz ? h2 : i2;
            float w = (dx ? r0 : 1.f - r0) * (dy ? r1 : 1.f - r1) * (dz ? r2 : 1.f - r2);
            sidx[tid][k] = (ix * 32 + iy) * 32 + iz;
            swt[tid][k] = w;
        }
    }
    __syncthreads();
    const ushort* hb = ht + (size_t)b * RRR_ * 128;
    // vectorized gather: 64 pts x 16 c8, each lane does i32x4 (8 bf16 ch) per corner
    for (int t = tid; t < 64 * 16; t += 256) {
        int c8 = t & 15, pt = t >> 4;
        float a[8] = {0.f, 0.f, 0.f, 0.f, 0.f, 0.f, 0.f, 0.f};
        #pragma unroll
        for (int k = 0; k < 8; ++k) {
            i32x4 raw = *(const i32x4*)(hb + (size_t)sidx[pt][k] * 128 + c8 * 8);
            ushort* u = (ushort*)&raw;
            float wk = swt[pt][k];
            #pragma unroll
            for (int j = 0; j < 8; ++j)
                a[j] = fmaf(wk, bf2f(u[j]), a[j]);
        }
        #pragma unroll
        for (int j = 0; j < 8; ++j)
            vp[pt][c8 * 8 + j] = a[j];
    }
    __syncthreads();
    const float invc = 1.0f / (16.0f * (float)N_);
    for (int t = tid; t < 64 * 128; t += 256) {
        int nl = t & 63;
        int c = t >> 6;
        int g = c >> 4;
        float sum = gstats[(64 + b * 8 + g) * 2 + 0];
        float ssq = gstats[(64 + b * 8 + g) * 2 + 1];
        float mean = sum * invc;
        float var = ssq * invc - mean * mean;
        float rstd = rsqrtf(var + 1e-5f);
        size_t o = ((size_t)(b * 128 + c)) * N_ + n0 + nl;
        float v = (out[o] - mean) * rstd * scale[c] + bias[c];
        v = v / (1.f + __expf(-v));
        out[o] = v + vp[nl][c];
    }
}

extern "C" void kernel_launch(void* const* d_in, const int* in_sizes, int n_in,
                              void* d_out, int out_size, void* d_ws, size_t ws_size,
                              hipStream_t stream) {
    const float* coords   = (const float*)d_in[0];
    const float* features = (const float*)d_in[1];
    const float* conv1_w  = (const float*)d_in[2];
    const float* conv1_b  = (const float*)d_in[3];
    const float* gn1_s    = (const float*)d_in[4];
    const float* gn1_b    = (const float*)d_in[5];
    const float* conv2_w  = (const float*)d_in[6];
    const float* conv2_b  = (const float*)d_in[7];
    const float* gn2_s    = (const float*)d_in[8];
    const float* gn2_b    = (const float*)d_in[9];
    const float* point_w  = (const float*)d_in[10];
    const float* point_b  = (const float*)d_in[11];
    const float* pgn_s    = (const float*)d_in[12];
    const float* pgn_b    = (const float*)d_in[13];
    float* out = (float*)d_out;
    float* ws = (float*)d_ws;

    float*  nc     = ws + OFF_NC;
    int*    vidx   = (int*)(ws + OFF_VIDX);
    ushort* wt1    = (ushort*)(ws + OFF_WT1);
    ushort* wt2    = (ushort*)(ws + OFF_WT2);
    ushort* c2out  = (ushort*)(ws + OFF_C2OUT);
    float*  cnt    = ws + OFF_CNT;
    float*  gsum   = ws + OFF_GSUM;
    ushort* gpad   = (ushort*)(ws + OFF_GPAD);
    ushort* act1   = (ushort*)(ws + OFF_ACT1);
    float*  gstats = ws + OFF_GSTATS;
    float*  bstats = ws + OFF_BSTATS;

    const float invc = 1.0f / (float)(RRR_ * 16);

    hipMemsetAsync(cnt, 0, MEMSET_FLOATS * sizeof(float), stream);

    k_coord_sum<<<dim3(64, B_), 256, 0, stream>>>(coords, bstats);
    k_coord_max<<<dim3(64, B_), 256, 0, stream>>>(coords, bstats);
    k_point_prep<<<B_ * N_ / 256, 256, 0, stream>>>(coords, bstats, nc, vidx, cnt);
    k_scatter_cl<<<dim3(N_ / 128, B_), 256, 0, stream>>>(features, vidx, gsum);
    k_gridmean_cl<<<B_ * RRR_ * 16 / 256, 256, 0, stream>>>(gsum, cnt, gpad);

    k_wtrans<64><<<(27 * 128 * 64 + 255) / 256, 256, 0, stream>>>(conv1_w, wt1);
    k_wtrans<128><<<(27 * 128 * 128 + 255) / 256, 256, 0, stream>>>(conv2_w, wt2);

    k_conv<64, true><<<dim3(8, 32, B_), 256, 0, stream>>>(gpad, wt1, conv1_b, act1, gstats, 0);
    k_gn_apply<true><<<B_ * RRR_ * 16 / 256, 256, 0, stream>>>(act1, gstats, gn1_s, gn1_b, 0, invc);

    k_conv<128, false><<<dim3(8, 32, B_), 256, 0, stream>>>(act1, wt2, conv2_b, c2out, gstats, 1);
    k_gn_apply<false><<<B_ * RRR_ * 16 / 256, 256, 0, stream>>>(c2out, gstats, gn2_s, gn2_b, 1, invc);

    k_point_mlp<<<B_ * N_ / 256, 256, 0, stream>>>(features, point_w, point_b, out, gstats);
    k_devox_final<<<B_ * N_ / 64, 256, 0, stream>>>(nc, c2out, gstats, pgn_s, pgn_b, out);
}

// Round 4
// 1297.668 us; speedup vs baseline: 8.8546x; 1.0757x over previous
//
#include <hip/hip_runtime.h>

typedef __attribute__((ext_vector_type(8))) short bf16x8;
typedef __attribute__((ext_vector_type(4))) float f32x4;
typedef __attribute__((ext_vector_type(4))) int i32x4;
typedef __attribute__((ext_vector_type(2))) int i32x2;

#define B_ 4
#define N_ 65536
#define RRR_ 32768
#define PADV_ 39304   // 34^3
#define PPLANE_ 1156  // 34*34

// ---- workspace layout (float offsets) ----
static const size_t OFF_NC     = 0;         //  [4][3][65536] f32
static const size_t OFF_VIDX   = 786432;    //  [4][65536] int
static const size_t OFF_WT1    = 1048576;   //  [27][128][64] bf16
static const size_t OFF_WT2    = 1159168;   //  [27][128][128] bf16
static const size_t OFF_C2OUT  = 1380352;   //  [4][32768][128] bf16
// ---- memset region starts here ----
static const size_t OFF_CNT    = 9768960;   //  [4][32768] f32
static const size_t OFF_GSUM   = 9900032;   //  [4][32768][64] f32
static const size_t OFF_GPAD   = 18288640;  //  [4][39304][64] bf16
static const size_t OFF_ACT1   = 23319552;  //  [4][39304][128] bf16
static const size_t OFF_GSTATS = 33381376;  //  [3][4][8][2] f32 raw sum/ssq
static const size_t OFF_BSTATS = 33381568;  //  [4][4] f32 (sum x3, maxbits)
static const size_t MEMSET_FLOATS = 33381584 - 9768960;

__device__ __forceinline__ ushort f2bf(float x) {
    union { float f; unsigned u; } c; c.f = x;
    unsigned r = c.u + 0x7fffu + ((c.u >> 16) & 1u);
    return (ushort)(r >> 16);
}
__device__ __forceinline__ float bf2f(ushort h) {
    union { unsigned u; float f; } c; c.u = ((unsigned)h) << 16;
    return c.f;
}

// ---------------- coord partial sums ----------------
__global__ __launch_bounds__(256) void k_coord_sum(const float* __restrict__ coords,
                                                   float* __restrict__ bstats) {
    int b = blockIdx.y;
    int tid = threadIdx.x;
    const float* cb = coords + (size_t)b * 3 * N_;
    float s0 = 0.f, s1 = 0.f, s2 = 0.f;
    for (int n = blockIdx.x * 256 + tid; n < N_; n += 64 * 256) {
        s0 += cb[n]; s1 += cb[N_ + n]; s2 += cb[2 * N_ + n];
    }
    #pragma unroll
    for (int off = 1; off < 64; off <<= 1) {
        s0 += __shfl_xor(s0, off);
        s1 += __shfl_xor(s1, off);
        s2 += __shfl_xor(s2, off);
    }
    if ((tid & 63) == 0) {
        atomicAdd(&bstats[b * 4 + 0], s0);
        atomicAdd(&bstats[b * 4 + 1], s1);
        atomicAdd(&bstats[b * 4 + 2], s2);
    }
}

// ---------------- coord max-norm (after sums) ----------------
__global__ __launch_bounds__(256) void k_coord_max(const float* __restrict__ coords,
                                                   float* __restrict__ bstats) {
    int b = blockIdx.y;
    int tid = threadIdx.x;
    const float invN = 1.0f / (float)N_;
    float m0 = bstats[b * 4 + 0] * invN;
    float m1 = bstats[b * 4 + 1] * invN;
    float m2 = bstats[b * 4 + 2] * invN;
    const float* cb = coords + (size_t)b * 3 * N_;
    float mx = 0.f;
    for (int n = blockIdx.x * 256 + tid; n < N_; n += 64 * 256) {
        float x = cb[n] - m0, y = cb[N_ + n] - m1, z = cb[2 * N_ + n] - m2;
        mx = fmaxf(mx, x * x + y * y + z * z);
    }
    #pragma unroll
    for (int off = 1; off < 64; off <<= 1)
        mx = fmaxf(mx, __shfl_xor(mx, off));
    if ((tid & 63) == 0)
        atomicMax((int*)&bstats[b * 4 + 3], __float_as_int(mx));
}

// ---------------- normalized coords, voxel idx, counts ----------------
__global__ __launch_bounds__(256) void k_point_prep(const float* __restrict__ coords,
                                                    const float* __restrict__ bstats,
                                                    float* __restrict__ nc,
                                                    int* __restrict__ vidx,
                                                    float* __restrict__ cnt) {
    int gid = blockIdx.x * 256 + threadIdx.x;
    int b = gid >> 16;
    int n = gid & (N_ - 1);
    const float invN = 1.0f / (float)N_;
    float m[3] = {bstats[b * 4 + 0] * invN, bstats[b * 4 + 1] * invN, bstats[b * 4 + 2] * invN};
    float den = 2.0f * sqrtf(__int_as_float(((const int*)bstats)[b * 4 + 3]));
    const float* cb = coords + (size_t)b * 3 * N_;
    int vi[3];
    #pragma unroll
    for (int d = 0; d < 3; ++d) {
        float cv = cb[(size_t)d * N_ + n];
        float t = (cv - m[d]) / den + 0.5f;
        t *= 32.0f;
        t = fminf(fmaxf(t, 0.0f), 31.0f);
        nc[((size_t)b * 3 + d) * N_ + n] = t;
        vi[d] = (int)rintf(t);
    }
    int flat = (vi[0] * 32 + vi[1]) * 32 + vi[2];
    vidx[(b << 16) + n] = flat;
    atomicAdd(&cnt[(b << 15) + flat], 1.0f);
}

// ---------------- scatter-add features (channels-last, LDS staged) ----------------
__global__ __launch_bounds__(256) void k_scatter_cl(const float* __restrict__ feats,
                                                    const int* __restrict__ vidx,
                                                    float* __restrict__ gsum) {
    __shared__ float lf[64 * 129];
    __shared__ int sidx[128];
    int tid = threadIdx.x;
    int b = blockIdx.y;
    int n0 = blockIdx.x * 128;
    for (int i = tid; i < 64 * 128; i += 256) {
        int ci = i >> 7, pt = i & 127;
        lf[ci * 129 + pt] = feats[((size_t)(b * 64 + ci)) * N_ + n0 + pt];
    }
    if (tid < 128) sidx[tid] = vidx[(b << 16) + n0 + tid];
    __syncthreads();
    for (int i = tid; i < 64 * 128; i += 256) {
        int ci = i & 63, pt = i >> 6;
        atomicAdd(&gsum[((size_t)(b << 15) + sidx[pt]) * 64 + ci], lf[ci * 129 + pt]);
    }
}

// ---------------- sum -> mean, to padded bf16 channels-last ----------------
__global__ __launch_bounds__(256) void k_gridmean_cl(const float* __restrict__ gsum,
                                                     const float* __restrict__ cnt,
                                                     ushort* __restrict__ gpad) {
    int idx = blockIdx.x * 256 + threadIdx.x;     // 4*32768*16
    int q = idx & 15;
    int vox = (idx >> 4) & 32767;
    int b = idx >> 19;
    float c = cnt[(b << 15) + vox];
    float inv = 1.0f / fmaxf(c, 1.0f);
    float4 v = *(const float4*)(gsum + (((size_t)(b << 15) + vox) << 6) + q * 4);
    int zz = vox >> 10, yy = (vox >> 5) & 31, xx = vox & 31;
    size_t o = ((size_t)b * PADV_ + (size_t)(zz + 1) * PPLANE_ + (yy + 1) * 34 + (xx + 1)) * 64 + q * 4;
    i32x2 pk;
    ushort* u = (ushort*)&pk;
    u[0] = f2bf(v.x * inv); u[1] = f2bf(v.y * inv);
    u[2] = f2bf(v.z * inv); u[3] = f2bf(v.w * inv);
    *(i32x2*)(gpad + o) = pk;
}

// ---------------- weight transpose [co][ci][27] f32 -> [27][co][ci] bf16 ----------------
template <int CI>
__global__ __launch_bounds__(256) void k_wtrans(const float* __restrict__ w,
                                                ushort* __restrict__ wt) {
    int idx = blockIdx.x * 256 + threadIdx.x;
    if (idx >= 27 * 128 * CI) return;
    int tap = idx / (128 * CI);
    int rem = idx - tap * 128 * CI;
    int co = rem / CI;
    int ci = rem - co * CI;
    wt[idx] = f2bf(w[((size_t)co * CI + ci) * 27 + tap]);
}

// ---------------- 3^3 conv as shift-GEMM MFMA ----------------
// LDS layout: [18 rows (3dz x 6dy)][34 x][4 quarters of 16B], quarter swizzled:
//   q_stored = q ^ ((x>>1)&3)  -> conflict-free b128 reads AND writes.
// GN_IN: apply GN+SiLU (layer-0 stats) to input during staging; halo cells -> 0.
template <int CI, bool PAD_OUT, bool GN_IN>
__global__ __launch_bounds__(256, 3) void k_conv(const ushort* __restrict__ inp,
                                                 const ushort* __restrict__ wt,
                                                 const float* __restrict__ bias,
                                                 ushort* __restrict__ outp,
                                                 float* __restrict__ gstats,
                                                 int layer,
                                                 const float* __restrict__ in_sc,
                                                 const float* __restrict__ in_bi,
                                                 float invc_in) {
    constexpr int NCHUNK = CI / 32;
    __shared__ i32x4 lds_mem[2448];            // 39168 B
    char* lds_raw = (char*)lds_mem;

    const int yq = blockIdx.x, z = blockIdx.y, b = blockIdx.z;
    const int y0 = yq * 4;
    const int tid = threadIdx.x;
    const int w = tid >> 6, l = tid & 63;
    const int lk = l >> 4;
    const int lr = l & 15;
    const int phalf = (w & 1) * 64, chalf = (w >> 1) * 64;

    const char* inb = (const char*)(inp + (size_t)b * PADV_ * CI);

    // ---- precompute staging slots (t4 = tid&3 is constant across j) ----
    const int t4 = tid & 3;
    int st_lds[10];
    int st_glb[10];       // byte offset within batch (chunk term added later)
    bool st_halo[10];
    #pragma unroll
    for (int j = 0; j < 10; ++j) {
        int idx = tid + j * 256;
        if (idx < 2448) {
            int r = idx >> 2;
            int x = r % 34;
            int row = r / 34;                  // 0..17
            int dz = row / 6, dy = row - dz * 6;
            int gz = z + dz, gy = y0 + dy;
            st_lds[j] = r * 64 + ((t4 ^ ((x >> 1) & 3)) << 4);
            st_glb[j] = (int)(((size_t)(gz * PPLANE_ + gy * 34 + x)) * CI + t4 * 8) * 2;
            st_halo[j] = (gz == 0) | (gz == 33) | (gy == 0) | (gy == 33) | (x == 0) | (x == 33);
        }
    }

    // ---- A-fragment read offsets [i][fx] (swizzle folded in) ----
    int aoff[4][3];
    #pragma unroll
    for (int i = 0; i < 4; ++i) {
        int pos = phalf + i * 16 + lr;
        int ly = pos >> 5, x = pos & 31;
        #pragma unroll
        for (int fx = 0; fx < 3; ++fx) {
            int xc = x + fx;
            aoff[i][fx] = (ly * 34 + xc) * 64 + ((lk ^ ((xc >> 1) & 3)) << 4);
        }
    }
    int boff[4];
    #pragma unroll
    for (int n = 0; n < 4; ++n)
        boff[n] = ((chalf + n * 16 + lr) * CI + lk * 8) * 2;
    const char* wtb = (const char*)wt;

    f32x4 acc[4][4];
    #pragma unroll
    for (int i = 0; i < 4; ++i)
        #pragma unroll
        for (int n = 0; n < 4; ++n)
            acc[i][n] = (f32x4){0.f, 0.f, 0.f, 0.f};

    #pragma unroll 1
    for (int chunk = 0; chunk < NCHUNK; ++chunk) {
        // per-chunk GN coefficients for this thread's 8 channels
        float ca[8], cb2[8];
        if (GN_IN) {
            int ch0 = chunk * 32 + t4 * 8;
            int g = ch0 >> 4;
            float sum = gstats[(b * 8 + g) * 2 + 0];
            float ssq = gstats[(b * 8 + g) * 2 + 1];
            float mean = sum * invc_in;
            float var = ssq * invc_in - mean * mean;
            float rstd = rsqrtf(var + 1e-5f);
            #pragma unroll
            for (int jj = 0; jj < 8; ++jj) {
                float s = in_sc[ch0 + jj];
                ca[jj] = rstd * s;
                cb2[jj] = in_bi[ch0 + jj] - mean * rstd * s;
            }
        }
        __syncthreads();
        {
            const char* srcb = inb + chunk * 64;
            #pragma unroll
            for (int j = 0; j < 10; ++j) {
                int idx = tid + j * 256;
                if (idx < 2448) {
                    i32x4 raw = *(const i32x4*)(srcb + st_glb[j]);
                    if (GN_IN) {
                        if (st_halo[j]) {
                            raw = (i32x4){0, 0, 0, 0};
                        } else {
                            ushort* u = (ushort*)&raw;
                            #pragma unroll
                            for (int jj = 0; jj < 8; ++jj) {
                                float v = fmaf(bf2f(u[jj]), ca[jj], cb2[jj]);
                                v = v / (1.f + __expf(-v));
                                u[jj] = f2bf(v);
                            }
                        }
                    }
                    *(i32x4*)(lds_raw + st_lds[j]) = raw;
                }
            }
        }
        __syncthreads();
        const char* wpc = wtb + chunk * 64;
        #pragma unroll
        for (int tap = 0; tap < 27; ++tap) {
            const int fz = tap / 9, r9 = tap - fz * 9;
            const int fy = r9 / 3, fx = r9 - fy * 3;
            const char* wp = wpc + (size_t)tap * (128 * CI * 2);
            bf16x8 bfrag[4];
            #pragma unroll
            for (int n = 0; n < 4; ++n) bfrag[n] = *(const bf16x8*)(wp + boff[n]);
            const int drow = (fz * 6 + fy) * 2176;
            bf16x8 afrag[4];
            #pragma unroll
            for (int i = 0; i < 4; ++i)
                afrag[i] = *(const bf16x8*)(lds_raw + drow + aoff[i][fx]);
            #pragma unroll
            for (int i = 0; i < 4; ++i)
                #pragma unroll
                for (int n = 0; n < 4; ++n)
                    acc[i][n] = __builtin_amdgcn_mfma_f32_16x16x32_bf16(afrag[i], bfrag[n], acc[i][n], 0, 0, 0);
        }
    }

    // epilogue: bias add + fused GN stats + bf16 pack via LDS + coalesced dump
    __syncthreads();
    ushort* outs = (ushort*)lds_mem;
    float bb[4];
    #pragma unroll
    for (int n = 0; n < 4; ++n) bb[n] = bias[chalf + n * 16 + lr];
    float sg[4] = {0.f, 0.f, 0.f, 0.f}, sq[4] = {0.f, 0.f, 0.f, 0.f};
    #pragma unroll
    for (int i = 0; i < 4; ++i) {
        int posb = phalf + i * 16 + lk * 4;
        #pragma unroll
        for (int n = 0; n < 4; ++n) {
            int co = chalf + n * 16 + lr;
            #pragma unroll
            for (int r = 0; r < 4; ++r) {
                float v = acc[i][n][r] + bb[n];
                sg[n] += v; sq[n] += v * v;
                outs[(posb + r) * 128 + co] = f2bf(v);
            }
        }
    }
    #pragma unroll
    for (int off = 1; off < 64; off <<= 1) {
        #pragma unroll
        for (int n = 0; n < 4; ++n) {
            sg[n] += __shfl_xor(sg[n], off);
            sq[n] += __shfl_xor(sq[n], off);
        }
    }
    if (l == 0) {
        int gbase = layer * 32 + b * 8 + (chalf >> 4);
        #pragma unroll
        for (int n = 0; n < 4; ++n) {
            atomicAdd(&gstats[(gbase + n) * 2 + 0], sg[n]);
            atomicAdd(&gstats[(gbase + n) * 2 + 1], sq[n]);
        }
    }
    __syncthreads();
    for (int idx = tid; idx < 2048; idx += 256) {
        int pos = idx >> 4, c8 = idx & 15;
        int ly = pos >> 5, x = pos & 31;
        size_t g;
        if (PAD_OUT)
            g = ((size_t)b * PADV_ + (size_t)(z + 1) * PPLANE_ + (y0 + ly + 1) * 34 + (x + 1)) * 128 + c8 * 8;
        else
            g = ((size_t)b * RRR_ + z * 1024 + (y0 + ly) * 32 + x) * 128 + c8 * 8;
        *(i32x4*)(outp + g) = *((i32x4*)lds_raw + idx);
    }
}

// ---------------- GN + SiLU apply (channels-last bf16, flat) ----------------
template <bool PAD>
__global__ __launch_bounds__(256) void k_gn_apply(ushort* __restrict__ x,
                                                  const float* __restrict__ gstats,
                                                  const float* __restrict__ sc,
                                                  const float* __restrict__ bi,
                                                  int layer, float invc) {
    int idx = blockIdx.x * 256 + threadIdx.x;   // 4*32768*16
    int c8 = idx & 15;
    int vox = (idx >> 4) & 32767;
    int b = idx >> 19;
    size_t base;
    if (PAD) {
        int zz = vox >> 10, yy = (vox >> 5) & 31, xx = vox & 31;
        base = ((size_t)b * PADV_ + (size_t)(zz + 1) * PPLANE_ + (yy + 1) * 34 + (xx + 1)) * 128 + c8 * 8;
    } else {
        base = ((size_t)b * RRR_ + vox) * 128 + c8 * 8;
    }
    int g = c8 >> 1;
    float sum = gstats[(layer * 32 + b * 8 + g) * 2 + 0];
    float ssq = gstats[(layer * 32 + b * 8 + g) * 2 + 1];
    float mean = sum * invc;
    float var = ssq * invc - mean * mean;
    float rstd = rsqrtf(var + 1e-5f);
    i32x4 raw = *(i32x4*)(x + base);
    ushort* u = (ushort*)&raw;
    #pragma unroll
    for (int j = 0; j < 8; ++j) {
        int co = c8 * 8 + j;
        float v = bf2f(u[j]);
        v = (v - mean) * rstd * sc[co] + bi[co];
        v = v / (1.f + __expf(-v));
        u[j] = f2bf(v);
    }
    *(i32x4*)(x + base) = raw;
}

// ---------------- point MLP (1x1 conv) + fused GN stats ----------------
__global__ __launch_bounds__(256) void k_point_mlp(const float* __restrict__ feats,
                                                   const float* __restrict__ w,
                                                   const float* __restrict__ pb,
                                                   float* __restrict__ out,
                                                   float* __restrict__ gstats) {
    __shared__ float wl[64 * 132];
    __shared__ float sred[4][16];
    int tid = threadIdx.x;
    for (int i = tid; i < 128 * 64; i += 256) {
        int o = i >> 6, c = i & 63;
        wl[c * 132 + o] = w[i];
    }
    __syncthreads();
    int gid = blockIdx.x * 256 + tid;
    int b = gid >> 16, n = gid & (N_ - 1);
    const float* fb = feats + (size_t)b * 64 * N_ + n;
    float acc[128];
    #pragma unroll
    for (int o = 0; o < 128; ++o) acc[o] = 0.f;
    for (int c = 0; c < 64; ++c) {
        float f = fb[(size_t)c * N_];
        const float4* wr4 = (const float4*)&wl[c * 132];
        #pragma unroll
        for (int o4 = 0; o4 < 32; ++o4) {
            float4 wv = wr4[o4];
            acc[4 * o4 + 0] = fmaf(f, wv.x, acc[4 * o4 + 0]);
            acc[4 * o4 + 1] = fmaf(f, wv.y, acc[4 * o4 + 1]);
            acc[4 * o4 + 2] = fmaf(f, wv.z, acc[4 * o4 + 2]);
            acc[4 * o4 + 3] = fmaf(f, wv.w, acc[4 * o4 + 3]);
        }
    }
    float* ob = out + (size_t)b * 128 * N_ + n;
    float sg[8] = {0.f}, sq[8] = {0.f};
    #pragma unroll
    for (int o = 0; o < 128; ++o) {
        float v = acc[o] + pb[o];
        ob[(size_t)o * N_] = v;
        sg[o >> 4] += v;
        sq[o >> 4] += v * v;
    }
    #pragma unroll
    for (int off = 1; off < 64; off <<= 1) {
        #pragma unroll
        for (int g = 0; g < 8; ++g) {
            sg[g] += __shfl_xor(sg[g], off);
            sq[g] += __shfl_xor(sq[g], off);
        }
    }
    int wv = tid >> 6, l = tid & 63;
    if (l == 0) {
        #pragma unroll
        for (int g = 0; g < 8; ++g) { sred[wv][g] = sg[g]; sred[wv][8 + g] = sq[g]; }
    }
    __syncthreads();
    if (tid < 16) {
        float v = sred[0][tid] + sred[1][tid] + sred[2][tid] + sred[3][tid];
        int g = tid & 7, part = tid >> 3;
        atomicAdd(&gstats[(64 + b * 8 + g) * 2 + part], v);
    }
}

// ---------------- devoxelize + point GN/SiLU + add ----------------
__global__ __launch_bounds__(256) void k_devox_final(const float* __restrict__ nc,
                                                     const ushort* __restrict__ ht,
                                                     const float* __restrict__ gstats,
                                                     const float* __restrict__ scale,
                                                     const float* __restrict__ bias,
                                                     float* __restrict__ out) {
    __shared__ float vp[64][129];
    __shared__ int sidx[64][8];
    __shared__ float swt[64][8];
    int tid = threadIdx.x;
    int blk = blockIdx.x;               // B * N/64 = 4096
    int b = blk >> 10;
    int n0 = (blk & 1023) * 64;
    if (tid < 64) {
        int n = n0 + tid;
        float f0 = nc[(size_t)b * 3 * N_ + n];
        float f1 = nc[((size_t)b * 3 + 1) * N_ + n];
        float f2 = nc[((size_t)b * 3 + 2) * N_ + n];
        float l0 = floorf(f0), l1 = floorf(f1), l2 = floorf(f2);
        float r0 = f0 - l0, r1 = f1 - l1, r2 = f2 - l2;
        int i0 = (int)l0, i1 = (int)l1, i2 = (int)l2;
        int h0 = min(i0 + 1, 31), h1 = min(i1 + 1, 31), h2 = min(i2 + 1, 31);
        #pragma unroll
        for (int k = 0; k < 8; ++k) {
            int dx = (k >> 2) & 1, dy = (k >> 1) & 1, dz = k & 1;
            int ix = dx ? h0 : i0, iy = dy ? h1 : i1, iz = dz ? h2 : i2;
            float w = (dx ? r0 : 1.f - r0) * (dy ? r1 : 1.f - r1) * (dz ? r2 : 1.f - r2);
            sidx[tid][k] = (ix * 32 + iy) * 32 + iz;
            swt[tid][k] = w;
        }
    }
    __syncthreads();
    const ushort* hb = ht + (size_t)b * RRR_ * 128;
    for (int t = tid; t < 64 * 16; t += 256) {
        int c8 = t & 15, pt = t >> 4;
        float a[8] = {0.f, 0.f, 0.f, 0.f, 0.f, 0.f, 0.f, 0.f};
        #pragma unroll
        for (int k = 0; k < 8; ++k) {
            i32x4 raw = *(const i32x4*)(hb + (size_t)sidx[pt][k] * 128 + c8 * 8);
            ushort* u = (ushort*)&raw;
            float wk = swt[pt][k];
            #pragma unroll
            for (int j = 0; j < 8; ++j)
                a[j] = fmaf(wk, bf2f(u[j]), a[j]);
        }
        #pragma unroll
        for (int j = 0; j < 8; ++j)
            vp[pt][c8 * 8 + j] = a[j];
    }
    __syncthreads();
    const float invc = 1.0f / (16.0f * (float)N_);
    for (int t = tid; t < 64 * 128; t += 256) {
        int nl = t & 63;
        int c = t >> 6;
        int g = c >> 4;
        float sum = gstats[(64 + b * 8 + g) * 2 + 0];
        float ssq = gstats[(64 + b * 8 + g) * 2 + 1];
        float mean = sum * invc;
        float var = ssq * invc - mean * mean;
        float rstd = rsqrtf(var + 1e-5f);
        size_t o = ((size_t)(b * 128 + c)) * N_ + n0 + nl;
        float v = (out[o] - mean) * rstd * scale[c] + bias[c];
        v = v / (1.f + __expf(-v));
        out[o] = v + vp[nl][c];
    }
}

extern "C" void kernel_launch(void* const* d_in, const int* in_sizes, int n_in,
                              void* d_out, int out_size, void* d_ws, size_t ws_size,
                              hipStream_t stream) {
    const float* coords   = (const float*)d_in[0];
    const float* features = (const float*)d_in[1];
    const float* conv1_w  = (const float*)d_in[2];
    const float* conv1_b  = (const float*)d_in[3];
    const float* gn1_s    = (const float*)d_in[4];
    const float* gn1_b    = (const float*)d_in[5];
    const float* conv2_w  = (const float*)d_in[6];
    const float* conv2_b  = (const float*)d_in[7];
    const float* gn2_s    = (const float*)d_in[8];
    const float* gn2_b    = (const float*)d_in[9];
    const float* point_w  = (const float*)d_in[10];
    const float* point_b  = (const float*)d_in[11];
    const float* pgn_s    = (const float*)d_in[12];
    const float* pgn_b    = (const float*)d_in[13];
    float* out = (float*)d_out;
    float* ws = (float*)d_ws;

    float*  nc     = ws + OFF_NC;
    int*    vidx   = (int*)(ws + OFF_VIDX);
    ushort* wt1    = (ushort*)(ws + OFF_WT1);
    ushort* wt2    = (ushort*)(ws + OFF_WT2);
    ushort* c2out  = (ushort*)(ws + OFF_C2OUT);
    float*  cnt    = ws + OFF_CNT;
    float*  gsum   = ws + OFF_GSUM;
    ushort* gpad   = (ushort*)(ws + OFF_GPAD);
    ushort* act1   = (ushort*)(ws + OFF_ACT1);
    float*  gstats = ws + OFF_GSTATS;
    float*  bstats = ws + OFF_BSTATS;

    const float invc = 1.0f / (float)(RRR_ * 16);

    hipMemsetAsync(cnt, 0, MEMSET_FLOATS * sizeof(float), stream);

    k_coord_sum<<<dim3(64, B_), 256, 0, stream>>>(coords, bstats);
    k_coord_max<<<dim3(64, B_), 256, 0, stream>>>(coords, bstats);
    k_point_prep<<<B_ * N_ / 256, 256, 0, stream>>>(coords, bstats, nc, vidx, cnt);
    k_scatter_cl<<<dim3(N_ / 128, B_), 256, 0, stream>>>(features, vidx, gsum);
    k_gridmean_cl<<<B_ * RRR_ * 16 / 256, 256, 0, stream>>>(gsum, cnt, gpad);

    k_wtrans<64><<<(27 * 128 * 64 + 255) / 256, 256, 0, stream>>>(conv1_w, wt1);
    k_wtrans<128><<<(27 * 128 * 128 + 255) / 256, 256, 0, stream>>>(conv2_w, wt2);

    k_conv<64, true, false><<<dim3(8, 32, B_), 256, 0, stream>>>(
        gpad, wt1, conv1_b, act1, gstats, 0, nullptr, nullptr, 0.f);

    k_conv<128, false, true><<<dim3(8, 32, B_), 256, 0, stream>>>(
        act1, wt2, conv2_b, c2out, gstats, 1, gn1_s, gn1_b, invc);
    k_gn_apply<false><<<B_ * RRR_ * 16 / 256, 256, 0, stream>>>(c2out, gstats, gn2_s, gn2_b, 1, invc);

    k_point_mlp<<<B_ * N_ / 256, 256, 0, stream>>>(features, point_w, point_b, out, gstats);
    k_devox_final<<<B_ * N_ / 64, 256, 0, stream>>>(nc, c2out, gstats, pgn_s, pgn_b, out);
}

// Round 5
// 1210.638 us; speedup vs baseline: 9.4911x; 1.0719x over previous
//
#include <hip/hip_runtime.h>

typedef __attribute__((ext_vector_type(8))) short bf16x8;
typedef __attribute__((ext_vector_type(4))) float f32x4;
typedef __attribute__((ext_vector_type(4))) int i32x4;
typedef __attribute__((ext_vector_type(2))) int i32x2;

#define B_ 4
#define N_ 65536
#define RRR_ 32768
#define PADV_ 39304   // 34^3
#define PPLANE_ 1156  // 34*34

// ---- workspace layout (float offsets) ----
static const size_t OFF_NC     = 0;         //  [4][3][65536] f32
static const size_t OFF_VIDX   = 786432;    //  [4][65536] int
static const size_t OFF_WT1    = 1048576;   //  [2ch][27][128][32] bf16 (quarter-swizzled)
static const size_t OFF_WT2    = 1159168;   //  [4ch][27][128][32] bf16 (quarter-swizzled)
static const size_t OFF_C2OUT  = 1380352;   //  [4][32768][128] bf16
// ---- memset region starts here ----
static const size_t OFF_CNT    = 9768960;   //  [4][32768] f32
static const size_t OFF_GSUM   = 9900032;   //  [4][32768][64] f32
static const size_t OFF_GPAD   = 18288640;  //  [4][39304][64] bf16
static const size_t OFF_ACT1   = 23319552;  //  [4][39304][128] bf16
static const size_t OFF_GSTATS = 33381376;  //  [3][4][8][2] f32 raw sum/ssq
static const size_t OFF_BSTATS = 33381568;  //  [4][4] f32 (sum x3, maxbits)
static const size_t MEMSET_FLOATS = 33381584 - 9768960;

__device__ __forceinline__ ushort f2bf(float x) {
    union { float f; unsigned u; } c; c.f = x;
    unsigned r = c.u + 0x7fffu + ((c.u >> 16) & 1u);
    return (ushort)(r >> 16);
}
__device__ __forceinline__ float bf2f(ushort h) {
    union { unsigned u; float f; } c; c.u = ((unsigned)h) << 16;
    return c.f;
}

// ---------------- coord partial sums ----------------
__global__ __launch_bounds__(256) void k_coord_sum(const float* __restrict__ coords,
                                                   float* __restrict__ bstats) {
    int b = blockIdx.y;
    int tid = threadIdx.x;
    const float* cb = coords + (size_t)b * 3 * N_;
    float s0 = 0.f, s1 = 0.f, s2 = 0.f;
    for (int n = blockIdx.x * 256 + tid; n < N_; n += 64 * 256) {
        s0 += cb[n]; s1 += cb[N_ + n]; s2 += cb[2 * N_ + n];
    }
    #pragma unroll
    for (int off = 1; off < 64; off <<= 1) {
        s0 += __shfl_xor(s0, off);
        s1 += __shfl_xor(s1, off);
        s2 += __shfl_xor(s2, off);
    }
    if ((tid & 63) == 0) {
        atomicAdd(&bstats[b * 4 + 0], s0);
        atomicAdd(&bstats[b * 4 + 1], s1);
        atomicAdd(&bstats[b * 4 + 2], s2);
    }
}

// ---------------- coord max-norm (after sums) ----------------
__global__ __launch_bounds__(256) void k_coord_max(const float* __restrict__ coords,
                                                   float* __restrict__ bstats) {
    int b = blockIdx.y;
    int tid = threadIdx.x;
    const float invN = 1.0f / (float)N_;
    float m0 = bstats[b * 4 + 0] * invN;
    float m1 = bstats[b * 4 + 1] * invN;
    float m2 = bstats[b * 4 + 2] * invN;
    const float* cb = coords + (size_t)b * 3 * N_;
    float mx = 0.f;
    for (int n = blockIdx.x * 256 + tid; n < N_; n += 64 * 256) {
        float x = cb[n] - m0, y = cb[N_ + n] - m1, z = cb[2 * N_ + n] - m2;
        mx = fmaxf(mx, x * x + y * y + z * z);
    }
    #pragma unroll
    for (int off = 1; off < 64; off <<= 1)
        mx = fmaxf(mx, __shfl_xor(mx, off));
    if ((tid & 63) == 0)
        atomicMax((int*)&bstats[b * 4 + 3], __float_as_int(mx));
}

// ---------------- normalized coords, voxel idx, counts ----------------
__global__ __launch_bounds__(256) void k_point_prep(const float* __restrict__ coords,
                                                    const float* __restrict__ bstats,
                                                    float* __restrict__ nc,
                                                    int* __restrict__ vidx,
                                                    float* __restrict__ cnt) {
    int gid = blockIdx.x * 256 + threadIdx.x;
    int b = gid >> 16;
    int n = gid & (N_ - 1);
    const float invN = 1.0f / (float)N_;
    float m[3] = {bstats[b * 4 + 0] * invN, bstats[b * 4 + 1] * invN, bstats[b * 4 + 2] * invN};
    float den = 2.0f * sqrtf(__int_as_float(((const int*)bstats)[b * 4 + 3]));
    const float* cb = coords + (size_t)b * 3 * N_;
    int vi[3];
    #pragma unroll
    for (int d = 0; d < 3; ++d) {
        float cv = cb[(size_t)d * N_ + n];
        float t = (cv - m[d]) / den + 0.5f;
        t *= 32.0f;
        t = fminf(fmaxf(t, 0.0f), 31.0f);
        nc[((size_t)b * 3 + d) * N_ + n] = t;
        vi[d] = (int)rintf(t);
    }
    int flat = (vi[0] * 32 + vi[1]) * 32 + vi[2];
    vidx[(b << 16) + n] = flat;
    atomicAdd(&cnt[(b << 15) + flat], 1.0f);
}

// ---------------- scatter-add features (channels-last, LDS staged) ----------------
__global__ __launch_bounds__(256) void k_scatter_cl(const float* __restrict__ feats,
                                                    const int* __restrict__ vidx,
                                                    float* __restrict__ gsum) {
    __shared__ float lf[64 * 129];
    __shared__ int sidx[128];
    int tid = threadIdx.x;
    int b = blockIdx.y;
    int n0 = blockIdx.x * 128;
    for (int i = tid; i < 64 * 128; i += 256) {
        int ci = i >> 7, pt = i & 127;
        lf[ci * 129 + pt] = feats[((size_t)(b * 64 + ci)) * N_ + n0 + pt];
    }
    if (tid < 128) sidx[tid] = vidx[(b << 16) + n0 + tid];
    __syncthreads();
    for (int i = tid; i < 64 * 128; i += 256) {
        int ci = i & 63, pt = i >> 6;
        atomicAdd(&gsum[((size_t)(b << 15) + sidx[pt]) * 64 + ci], lf[ci * 129 + pt]);
    }
}

// ---------------- sum -> mean, to padded bf16 channels-last ----------------
__global__ __launch_bounds__(256) void k_gridmean_cl(const float* __restrict__ gsum,
                                                     const float* __restrict__ cnt,
                                                     ushort* __restrict__ gpad) {
    int idx = blockIdx.x * 256 + threadIdx.x;     // 4*32768*16
    int q = idx & 15;
    int vox = (idx >> 4) & 32767;
    int b = idx >> 19;
    float c = cnt[(b << 15) + vox];
    float inv = 1.0f / fmaxf(c, 1.0f);
    float4 v = *(const float4*)(gsum + (((size_t)(b << 15) + vox) << 6) + q * 4);
    int zz = vox >> 10, yy = (vox >> 5) & 31, xx = vox & 31;
    size_t o = ((size_t)b * PADV_ + (size_t)(zz + 1) * PPLANE_ + (yy + 1) * 34 + (xx + 1)) * 64 + q * 4;
    i32x2 pk;
    ushort* u = (ushort*)&pk;
    u[0] = f2bf(v.x * inv); u[1] = f2bf(v.y * inv);
    u[2] = f2bf(v.z * inv); u[3] = f2bf(v.w * inv);
    *(i32x2*)(gpad + o) = pk;
}

// ---------------- weight transpose to [chunk][tap][co][32ci], quarter-swizzled ----------------
// stored quarter qm of row co holds logical quarter (qm ^ s(co)), s(co)=(co^(co>>2))&3
template <int CI>
__global__ __launch_bounds__(256) void k_wtrans(const float* __restrict__ w,
                                                ushort* __restrict__ wt) {
    int idx = blockIdx.x * 256 + threadIdx.x;
    if (idx >= 27 * 128 * CI) return;
    int within = idx & 31;
    int qm = within >> 3, e = within & 7;
    int t2 = idx >> 5;
    int co = t2 & 127;
    int t3 = t2 >> 7;
    int tap = t3 % 27;
    int chunk = t3 / 27;
    int s = (co & 3) ^ ((co >> 2) & 3);
    int ci = chunk * 32 + ((qm ^ s) << 3) + e;
    wt[idx] = f2bf(w[((size_t)co * CI + ci) * 27 + tap]);
}

// ---------------- 3^3 conv as shift-GEMM MFMA, pipelined B through LDS ring ----------------
template <int CI, bool PAD_OUT, bool GN_IN>
__global__ __launch_bounds__(256, 2) void k_conv(const ushort* __restrict__ inp,
                                                 const ushort* __restrict__ wt,
                                                 const float* __restrict__ bias,
                                                 ushort* __restrict__ outp,
                                                 float* __restrict__ gstats,
                                                 int layer,
                                                 const float* __restrict__ in_sc,
                                                 const float* __restrict__ in_bi,
                                                 float invc_in) {
    constexpr int NCHUNK = CI / 32;
    __shared__ char lds_all[39168 + 16384];
    char* slab = lds_all;                 // A slab: [18 rows][34 x][4 sw-quarters] bf16
    char* bufB = lds_all + 39168;         // B ring: 2 x 8192 B

    const int yq = blockIdx.x, z = blockIdx.y, b = blockIdx.z;
    const int y0 = yq * 4;
    const int tid = threadIdx.x;
    const int w = tid >> 6, l = tid & 63;
    const int lk = l >> 4;
    const int lr = l & 15;
    const int phalf = (w & 1) * 64, chalf = (w >> 1) * 64;

    const char* inb = (const char*)(inp + (size_t)b * PADV_ * CI);

    // ---- staging slots ----
    const int t4 = tid & 3;
    int st_lds[10];
    int st_glb[10];
    bool st_halo[10];
    #pragma unroll
    for (int j = 0; j < 10; ++j) {
        int idx = tid + j * 256;
        if (idx < 2448) {
            int r = idx >> 2;
            int x = r % 34;
            int row = r / 34;
            int dz = row / 6, dy = row - dz * 6;
            int gz = z + dz, gy = y0 + dy;
            st_lds[j] = r * 64 + ((t4 ^ ((x >> 1) & 3)) << 4);
            st_glb[j] = (int)(((size_t)(gz * PPLANE_ + gy * 34 + x)) * CI + t4 * 8) * 2;
            st_halo[j] = (gz == 0) | (gz == 33) | (gy == 0) | (gy == 33) | (x == 0) | (x == 33);
        }
    }

    // ---- A-fragment read offsets [i][fx] ----
    int aoff[4][3];
    #pragma unroll
    for (int i = 0; i < 4; ++i) {
        int pos = phalf + i * 16 + lr;
        int ly = pos >> 5, x = pos & 31;
        #pragma unroll
        for (int fx = 0; fx < 3; ++fx) {
            int xc = x + fx;
            aoff[i][fx] = (ly * 34 + xc) * 64 + ((lk ^ ((xc >> 1) & 3)) << 4);
        }
    }
    // ---- B-fragment read base (quarter-swizzle folded) ----
    const int s_lr = (lr & 3) ^ ((lr >> 2) & 3);
    const int bb0 = (chalf + lr) * 64 + ((lk ^ s_lr) << 4);   // + n*1024

    const char* wtb = (const char*)wt;

    f32x4 acc[4][4];
    #pragma unroll
    for (int i = 0; i < 4; ++i)
        #pragma unroll
        for (int n = 0; n < 4; ++n)
            acc[i][n] = (f32x4){0.f, 0.f, 0.f, 0.f};

    #pragma unroll 1
    for (int chunk = 0; chunk < NCHUNK; ++chunk) {
        const char* wB = wtb + (size_t)chunk * 27 * 8192;
        // issue B prefetch for taps 0 and 1
        i32x4 bre[2][2];
        bre[0][0] = *(const i32x4*)(wB + tid * 16);
        bre[0][1] = *(const i32x4*)(wB + 4096 + tid * 16);
        bre[1][0] = *(const i32x4*)(wB + 8192 + tid * 16);
        bre[1][1] = *(const i32x4*)(wB + 8192 + 4096 + tid * 16);

        // per-chunk GN coefficients
        float ca[8], cb2[8];
        if (GN_IN) {
            int ch0 = chunk * 32 + t4 * 8;
            int g = ch0 >> 4;
            float sum = gstats[(b * 8 + g) * 2 + 0];
            float ssq = gstats[(b * 8 + g) * 2 + 1];
            float mean = sum * invc_in;
            float var = ssq * invc_in - mean * mean;
            float rstd = rsqrtf(var + 1e-5f);
            #pragma unroll
            for (int jj = 0; jj < 8; ++jj) {
                float s = in_sc[ch0 + jj];
                ca[jj] = rstd * s;
                cb2[jj] = in_bi[ch0 + jj] - mean * rstd * s;
            }
        }
        // A-slab staging
        {
            const char* srcb = inb + chunk * 64;
            #pragma unroll
            for (int j = 0; j < 10; ++j) {
                int idx = tid + j * 256;
                if (idx < 2448) {
                    i32x4 raw = *(const i32x4*)(srcb + st_glb[j]);
                    if (GN_IN) {
                        if (st_halo[j]) {
                            raw = (i32x4){0, 0, 0, 0};
                        } else {
                            ushort* u = (ushort*)&raw;
                            #pragma unroll
                            for (int jj = 0; jj < 8; ++jj) {
                                float v = fmaf(bf2f(u[jj]), ca[jj], cb2[jj]);
                                v = v / (1.f + __expf(-v));
                                u[jj] = f2bf(v);
                            }
                        }
                    }
                    *(i32x4*)(slab + st_lds[j]) = raw;
                }
            }
        }
        // write tap0 into buf0
        *(i32x4*)(bufB + tid * 16) = bre[0][0];
        *(i32x4*)(bufB + 4096 + tid * 16) = bre[0][1];
        __syncthreads();

        #pragma unroll
        for (int t = 0; t < 27; ++t) {
            // issue loads for tap t+2
            if (t + 2 < 27) {
                const char* wp = wB + (t + 2) * 8192;
                bre[t & 1][0] = *(const i32x4*)(wp + tid * 16);
                bre[t & 1][1] = *(const i32x4*)(wp + 4096 + tid * 16);
            }
            // ds_write tap t+1 (compiler inserts counted vmcnt here)
            if (t + 1 < 27) {
                char* bw = bufB + ((t + 1) & 1) * 8192;
                *(i32x4*)(bw + tid * 16) = bre[(t + 1) & 1][0];
                *(i32x4*)(bw + 4096 + tid * 16) = bre[(t + 1) & 1][1];
            }
            // compute tap t
            const char* brd = bufB + (t & 1) * 8192;
            bf16x8 bfrag[4];
            #pragma unroll
            for (int n = 0; n < 4; ++n)
                bfrag[n] = *(const bf16x8*)(brd + bb0 + n * 1024);
            const int fz = t / 9, r9 = t - fz * 9;
            const int fy = r9 / 3, fx = r9 - fy * 3;
            const int drow = (fz * 6 + fy) * 2176;
            bf16x8 afrag[4];
            #pragma unroll
            for (int i = 0; i < 4; ++i)
                afrag[i] = *(const bf16x8*)(slab + drow + aoff[i][fx]);
            #pragma unroll
            for (int i = 0; i < 4; ++i)
                #pragma unroll
                for (int n = 0; n < 4; ++n)
                    acc[i][n] = __builtin_amdgcn_mfma_f32_16x16x32_bf16(afrag[i], bfrag[n], acc[i][n], 0, 0, 0);
            // phase close: keep global loads in flight (no vmcnt drain)
            __builtin_amdgcn_sched_barrier(0);
            asm volatile("s_waitcnt lgkmcnt(0)" ::: "memory");
            __builtin_amdgcn_s_barrier();
            __builtin_amdgcn_sched_barrier(0);
        }
    }

    // epilogue: bias add + fused GN stats + bf16 pack via LDS + coalesced dump
    __syncthreads();
    ushort* outs = (ushort*)lds_all;
    float bb[4];
    #pragma unroll
    for (int n = 0; n < 4; ++n) bb[n] = bias[chalf + n * 16 + lr];
    float sg[4] = {0.f, 0.f, 0.f, 0.f}, sq[4] = {0.f, 0.f, 0.f, 0.f};
    #pragma unroll
    for (int i = 0; i < 4; ++i) {
        int posb = phalf + i * 16 + lk * 4;
        #pragma unroll
        for (int n = 0; n < 4; ++n) {
            int co = chalf + n * 16 + lr;
            #pragma unroll
            for (int r = 0; r < 4; ++r) {
                float v = acc[i][n][r] + bb[n];
                sg[n] += v; sq[n] += v * v;
                outs[(posb + r) * 128 + co] = f2bf(v);
            }
        }
    }
    #pragma unroll
    for (int off = 1; off < 64; off <<= 1) {
        #pragma unroll
        for (int n = 0; n < 4; ++n) {
            sg[n] += __shfl_xor(sg[n], off);
            sq[n] += __shfl_xor(sq[n], off);
        }
    }
    if (l == 0) {
        int gbase = layer * 32 + b * 8 + (chalf >> 4);
        #pragma unroll
        for (int n = 0; n < 4; ++n) {
            atomicAdd(&gstats[(gbase + n) * 2 + 0], sg[n]);
            atomicAdd(&gstats[(gbase + n) * 2 + 1], sq[n]);
        }
    }
    __syncthreads();
    for (int idx = tid; idx < 2048; idx += 256) {
        int pos = idx >> 4, c8 = idx & 15;
        int ly = pos >> 5, x = pos & 31;
        size_t g;
        if (PAD_OUT)
            g = ((size_t)b * PADV_ + (size_t)(z + 1) * PPLANE_ + (y0 + ly + 1) * 34 + (x + 1)) * 128 + c8 * 8;
        else
            g = ((size_t)b * RRR_ + z * 1024 + (y0 + ly) * 32 + x) * 128 + c8 * 8;
        *(i32x4*)(outp + g) = *((i32x4*)lds_all + idx);
    }
}

// ---------------- GN + SiLU apply (channels-last bf16, flat) ----------------
template <bool PAD>
__global__ __launch_bounds__(256) void k_gn_apply(ushort* __restrict__ x,
                                                  const float* __restrict__ gstats,
                                                  const float* __restrict__ sc,
                                                  const float* __restrict__ bi,
                                                  int layer, float invc) {
    int idx = blockIdx.x * 256 + threadIdx.x;   // 4*32768*16
    int c8 = idx & 15;
    int vox = (idx >> 4) & 32767;
    int b = idx >> 19;
    size_t base;
    if (PAD) {
        int zz = vox >> 10, yy = (vox >> 5) & 31, xx = vox & 31;
        base = ((size_t)b * PADV_ + (size_t)(zz + 1) * PPLANE_ + (yy + 1) * 34 + (xx + 1)) * 128 + c8 * 8;
    } else {
        base = ((size_t)b * RRR_ + vox) * 128 + c8 * 8;
    }
    int g = c8 >> 1;
    float sum = gstats[(layer * 32 + b * 8 + g) * 2 + 0];
    float ssq = gstats[(layer * 32 + b * 8 + g) * 2 + 1];
    float mean = sum * invc;
    float var = ssq * invc - mean * mean;
    float rstd = rsqrtf(var + 1e-5f);
    i32x4 raw = *(i32x4*)(x + base);
    ushort* u = (ushort*)&raw;
    #pragma unroll
    for (int j = 0; j < 8; ++j) {
        int co = c8 * 8 + j;
        float v = bf2f(u[j]);
        v = (v - mean) * rstd * sc[co] + bi[co];
        v = v / (1.f + __expf(-v));
        u[j] = f2bf(v);
    }
    *(i32x4*)(x + base) = raw;
}

// ---------------- point MLP (1x1 conv) + fused GN stats ----------------
__global__ __launch_bounds__(256) void k_point_mlp(const float* __restrict__ feats,
                                                   const float* __restrict__ w,
                                                   const float* __restrict__ pb,
                                                   float* __restrict__ out,
                                                   float* __restrict__ gstats) {
    __shared__ float wl[64 * 132];
    __shared__ float sred[4][16];
    int tid = threadIdx.x;
    for (int i = tid; i < 128 * 64; i += 256) {
        int o = i >> 6, c = i & 63;
        wl[c * 132 + o] = w[i];
    }
    __syncthreads();
    int gid = blockIdx.x * 256 + tid;
    int b = gid >> 16, n = gid & (N_ - 1);
    const float* fb = feats + (size_t)b * 64 * N_ + n;
    float acc[128];
    #pragma unroll
    for (int o = 0; o < 128; ++o) acc[o] = 0.f;
    for (int c = 0; c < 64; ++c) {
        float f = fb[(size_t)c * N_];
        const float4* wr4 = (const float4*)&wl[c * 132];
        #pragma unroll
        for (int o4 = 0; o4 < 32; ++o4) {
            float4 wv = wr4[o4];
            acc[4 * o4 + 0] = fmaf(f, wv.x, acc[4 * o4 + 0]);
            acc[4 * o4 + 1] = fmaf(f, wv.y, acc[4 * o4 + 1]);
            acc[4 * o4 + 2] = fmaf(f, wv.z, acc[4 * o4 + 2]);
            acc[4 * o4 + 3] = fmaf(f, wv.w, acc[4 * o4 + 3]);
        }
    }
    float* ob = out + (size_t)b * 128 * N_ + n;
    float sg[8] = {0.f}, sq[8] = {0.f};
    #pragma unroll
    for (int o = 0; o < 128; ++o) {
        float v = acc[o] + pb[o];
        ob[(size_t)o * N_] = v;
        sg[o >> 4] += v;
        sq[o >> 4] += v * v;
    }
    #pragma unroll
    for (int off = 1; off < 64; off <<= 1) {
        #pragma unroll
        for (int g = 0; g < 8; ++g) {
            sg[g] += __shfl_xor(sg[g], off);
            sq[g] += __shfl_xor(sq[g], off);
        }
    }
    int wv = tid >> 6, l = tid & 63;
    if (l == 0) {
        #pragma unroll
        for (int g = 0; g < 8; ++g) { sred[wv][g] = sg[g]; sred[wv][8 + g] = sq[g]; }
    }
    __syncthreads();
    if (tid < 16) {
        float v = sred[0][tid] + sred[1][tid] + sred[2][tid] + sred[3][tid];
        int g = tid & 7, part = tid >> 3;
        atomicAdd(&gstats[(64 + b * 8 + g) * 2 + part], v);
    }
}

// ---------------- devoxelize + point GN/SiLU + add ----------------
__global__ __launch_bounds__(256) void k_devox_final(const float* __restrict__ nc,
                                                     const ushort* __restrict__ ht,
                                                     const float* __restrict__ gstats,
                                                     const float* __restrict__ scale,
                                                     const float* __restrict__ bias,
                                                     float* __restrict__ out) {
    __shared__ float vp[64][129];
    __shared__ int sidx[64][8];
    __shared__ float swt[64][8];
    int tid = threadIdx.x;
    int blk = blockIdx.x;               // B * N/64 = 4096
    int b = blk >> 10;
    int n0 = (blk & 1023) * 64;
    if (tid < 64) {
        int n = n0 + tid;
        float f0 = nc[(size_t)b * 3 * N_ + n];
        float f1 = nc[((size_t)b * 3 + 1) * N_ + n];
        float f2 = nc[((size_t)b * 3 + 2) * N_ + n];
        float l0 = floorf(f0), l1 = floorf(f1), l2 = floorf(f2);
        float r0 = f0 - l0, r1 = f1 - l1, r2 = f2 - l2;
        int i0 = (int)l0, i1 = (int)l1, i2 = (int)l2;
        int h0 = min(i0 + 1, 31), h1 = min(i1 + 1, 31), h2 = min(i2 + 1, 31);
        #pragma unroll
        for (int k = 0; k < 8; ++k) {
            int dx = (k >> 2) & 1, dy = (k >> 1) & 1, dz = k & 1;
            int ix = dx ? h0 : i0, iy = dy ? h1 : i1, iz = dz ? h2 : i2;
            float w = (dx ? r0 : 1.f - r0) * (dy ? r1 : 1.f - r1) * (dz ? r2 : 1.f - r2);
            sidx[tid][k] = (ix * 32 + iy) * 32 + iz;
            swt[tid][k] = w;
        }
    }
    __syncthreads();
    const ushort* hb = ht + (size_t)b * RRR_ * 128;
    for (int t = tid; t < 64 * 16; t += 256) {
        int c8 = t & 15, pt = t >> 4;
        float a[8] = {0.f, 0.f, 0.f, 0.f, 0.f, 0.f, 0.f, 0.f};
        #pragma unroll
        for (int k = 0; k < 8; ++k) {
            i32x4 raw = *(const i32x4*)(hb + (size_t)sidx[pt][k] * 128 + c8 * 8);
            ushort* u = (ushort*)&raw;
            float wk = swt[pt][k];
            #pragma unroll
            for (int j = 0; j < 8; ++j)
                a[j] = fmaf(wk, bf2f(u[j]), a[j]);
        }
        #pragma unroll
        for (int j = 0; j < 8; ++j)
            vp[pt][c8 * 8 + j] = a[j];
    }
    __syncthreads();
    const float invc = 1.0f / (16.0f * (float)N_);
    for (int t = tid; t < 64 * 128; t += 256) {
        int nl = t & 63;
        int c = t >> 6;
        int g = c >> 4;
        float sum = gstats[(64 + b * 8 + g) * 2 + 0];
        float ssq = gstats[(64 + b * 8 + g) * 2 + 1];
        float mean = sum * invc;
        float var = ssq * invc - mean * mean;
        float rstd = rsqrtf(var + 1e-5f);
        size_t o = ((size_t)(b * 128 + c)) * N_ + n0 + nl;
        float v = (out[o] - mean) * rstd * scale[c] + bias[c];
        v = v / (1.f + __expf(-v));
        out[o] = v + vp[nl][c];
    }
}

extern "C" void kernel_launch(void* const* d_in, const int* in_sizes, int n_in,
                              void* d_out, int out_size, void* d_ws, size_t ws_size,
                              hipStream_t stream) {
    const float* coords   = (const float*)d_in[0];
    const float* features = (const float*)d_in[1];
    const float* conv1_w  = (const float*)d_in[2];
    const float* conv1_b  = (const float*)d_in[3];
    const float* gn1_s    = (const float*)d_in[4];
    const float* gn1_b    = (const float*)d_in[5];
    const float* conv2_w  = (const float*)d_in[6];
    const float* conv2_b  = (const float*)d_in[7];
    const float* gn2_s    = (const float*)d_in[8];
    const float* gn2_b    = (const float*)d_in[9];
    const float* point_w  = (const float*)d_in[10];
    const float* point_b  = (const float*)d_in[11];
    const float* pgn_s    = (const float*)d_in[12];
    const float* pgn_b    = (const float*)d_in[13];
    float* out = (float*)d_out;
    float* ws = (float*)d_ws;

    float*  nc     = ws + OFF_NC;
    int*    vidx   = (int*)(ws + OFF_VIDX);
    ushort* wt1    = (ushort*)(ws + OFF_WT1);
    ushort* wt2    = (ushort*)(ws + OFF_WT2);
    ushort* c2out  = (ushort*)(ws + OFF_C2OUT);
    float*  cnt    = ws + OFF_CNT;
    float*  gsum   = ws + OFF_GSUM;
    ushort* gpad   = (ushort*)(ws + OFF_GPAD);
    ushort* act1   = (ushort*)(ws + OFF_ACT1);
    float*  gstats = ws + OFF_GSTATS;
    float*  bstats = ws + OFF_BSTATS;

    const float invc = 1.0f / (float)(RRR_ * 16);

    hipMemsetAsync(cnt, 0, MEMSET_FLOATS * sizeof(float), stream);

    k_coord_sum<<<dim3(64, B_), 256, 0, stream>>>(coords, bstats);
    k_coord_max<<<dim3(64, B_), 256, 0, stream>>>(coords, bstats);
    k_point_prep<<<B_ * N_ / 256, 256, 0, stream>>>(coords, bstats, nc, vidx, cnt);
    k_scatter_cl<<<dim3(N_ / 128, B_), 256, 0, stream>>>(features, vidx, gsum);
    k_gridmean_cl<<<B_ * RRR_ * 16 / 256, 256, 0, stream>>>(gsum, cnt, gpad);

    k_wtrans<64><<<(27 * 128 * 64 + 255) / 256, 256, 0, stream>>>(conv1_w, wt1);
    k_wtrans<128><<<(27 * 128 * 128 + 255) / 256, 256, 0, stream>>>(conv2_w, wt2);

    k_conv<64, true, false><<<dim3(8, 32, B_), 256, 0, stream>>>(
        gpad, wt1, conv1_b, act1, gstats, 0, nullptr, nullptr, 0.f);

    k_conv<128, false, true><<<dim3(8, 32, B_), 256, 0, stream>>>(
        act1, wt2, conv2_b, c2out, gstats, 1, gn1_s, gn1_b, invc);
    k_gn_apply<false><<<B_ * RRR_ * 16 / 256, 256, 0, stream>>>(c2out, gstats, gn2_s, gn2_b, 1, invc);

    k_point_mlp<<<B_ * N_ / 256, 256, 0, stream>>>(features, point_w, point_b, out, gstats);
    k_devox_final<<<B_ * N_ / 64, 256, 0, stream>>>(nc, c2out, gstats, pgn_s, pgn_b, out);
}

// Round 6
// 1011.449 us; speedup vs baseline: 11.3602x; 1.1969x over previous
//
#include <hip/hip_runtime.h>

typedef __attribute__((ext_vector_type(8))) short bf16x8;
typedef __attribute__((ext_vector_type(4))) float f32x4;
typedef __attribute__((ext_vector_type(4))) int i32x4;
typedef __attribute__((ext_vector_type(2))) int i32x2;

#define B_ 4
#define N_ 65536
#define RRR_ 32768
#define PADV_ 39304   // 34^3
#define PPLANE_ 1156  // 34*34

// ---- workspace layout (float offsets) ----
static const size_t OFF_NC     = 0;         //  [4][3][65536] f32
static const size_t OFF_VIDX   = 786432;    //  [4][65536] int
static const size_t OFF_WT1    = 1048576;   //  [27][128][64] bf16
static const size_t OFF_WT2    = 1159168;   //  [27][128][128] bf16
static const size_t OFF_C2OUT  = 1380352;   //  [4][32768][128] bf16
// ---- memset region starts here ----
static const size_t OFF_CNT    = 9768960;   //  [4][32768] f32
static const size_t OFF_GSUM   = 9900032;   //  [4][32768][64] f32
static const size_t OFF_GPAD   = 18288640;  //  [4][39304][64] bf16
static const size_t OFF_ACT1   = 23319552;  //  [4][39304][128] bf16
static const size_t OFF_GSTATS = 33381376;  //  [3][4][8][2] f32 raw sum/ssq
static const size_t OFF_BSTATS = 33381568;  //  [4][4] f32 (sum x3, maxbits)
static const size_t MEMSET_FLOATS = 33381584 - 9768960;

__device__ __forceinline__ ushort f2bf(float x) {
    union { float f; unsigned u; } c; c.f = x;
    unsigned r = c.u + 0x7fffu + ((c.u >> 16) & 1u);
    return (ushort)(r >> 16);
}
__device__ __forceinline__ float bf2f(ushort h) {
    union { unsigned u; float f; } c; c.u = ((unsigned)h) << 16;
    return c.f;
}

// ---------------- coord partial sums ----------------
__global__ __launch_bounds__(256) void k_coord_sum(const float* __restrict__ coords,
                                                   float* __restrict__ bstats) {
    int b = blockIdx.y;
    int tid = threadIdx.x;
    const float* cb = coords + (size_t)b * 3 * N_;
    float s0 = 0.f, s1 = 0.f, s2 = 0.f;
    for (int n = blockIdx.x * 256 + tid; n < N_; n += 64 * 256) {
        s0 += cb[n]; s1 += cb[N_ + n]; s2 += cb[2 * N_ + n];
    }
    #pragma unroll
    for (int off = 1; off < 64; off <<= 1) {
        s0 += __shfl_xor(s0, off);
        s1 += __shfl_xor(s1, off);
        s2 += __shfl_xor(s2, off);
    }
    if ((tid & 63) == 0) {
        atomicAdd(&bstats[b * 4 + 0], s0);
        atomicAdd(&bstats[b * 4 + 1], s1);
        atomicAdd(&bstats[b * 4 + 2], s2);
    }
}

// ---------------- coord max-norm (after sums) ----------------
__global__ __launch_bounds__(256) void k_coord_max(const float* __restrict__ coords,
                                                   float* __restrict__ bstats) {
    int b = blockIdx.y;
    int tid = threadIdx.x;
    const float invN = 1.0f / (float)N_;
    float m0 = bstats[b * 4 + 0] * invN;
    float m1 = bstats[b * 4 + 1] * invN;
    float m2 = bstats[b * 4 + 2] * invN;
    const float* cb = coords + (size_t)b * 3 * N_;
    float mx = 0.f;
    for (int n = blockIdx.x * 256 + tid; n < N_; n += 64 * 256) {
        float x = cb[n] - m0, y = cb[N_ + n] - m1, z = cb[2 * N_ + n] - m2;
        mx = fmaxf(mx, x * x + y * y + z * z);
    }
    #pragma unroll
    for (int off = 1; off < 64; off <<= 1)
        mx = fmaxf(mx, __shfl_xor(mx, off));
    if ((tid & 63) == 0)
        atomicMax((int*)&bstats[b * 4 + 3], __float_as_int(mx));
}

// ---------------- normalized coords, voxel idx, counts ----------------
__global__ __launch_bounds__(256) void k_point_prep(const float* __restrict__ coords,
                                                    const float* __restrict__ bstats,
                                                    float* __restrict__ nc,
                                                    int* __restrict__ vidx,
                                                    float* __restrict__ cnt) {
    int gid = blockIdx.x * 256 + threadIdx.x;
    int b = gid >> 16;
    int n = gid & (N_ - 1);
    const float invN = 1.0f / (float)N_;
    float m[3] = {bstats[b * 4 + 0] * invN, bstats[b * 4 + 1] * invN, bstats[b * 4 + 2] * invN};
    float den = 2.0f * sqrtf(__int_as_float(((const int*)bstats)[b * 4 + 3]));
    const float* cb = coords + (size_t)b * 3 * N_;
    int vi[3];
    #pragma unroll
    for (int d = 0; d < 3; ++d) {
        float cv = cb[(size_t)d * N_ + n];
        float t = (cv - m[d]) / den + 0.5f;
        t *= 32.0f;
        t = fminf(fmaxf(t, 0.0f), 31.0f);
        nc[((size_t)b * 3 + d) * N_ + n] = t;
        vi[d] = (int)rintf(t);
    }
    int flat = (vi[0] * 32 + vi[1]) * 32 + vi[2];
    vidx[(b << 16) + n] = flat;
    atomicAdd(&cnt[(b << 15) + flat], 1.0f);
}

// ---------------- scatter-add features (channels-last, LDS staged) ----------------
__global__ __launch_bounds__(256) void k_scatter_cl(const float* __restrict__ feats,
                                                    const int* __restrict__ vidx,
                                                    float* __restrict__ gsum) {
    __shared__ float lf[64 * 129];
    __shared__ int sidx[128];
    int tid = threadIdx.x;
    int b = blockIdx.y;
    int n0 = blockIdx.x * 128;
    for (int i = tid; i < 64 * 128; i += 256) {
        int ci = i >> 7, pt = i & 127;
        lf[ci * 129 + pt] = feats[((size_t)(b * 64 + ci)) * N_ + n0 + pt];
    }
    if (tid < 128) sidx[tid] = vidx[(b << 16) + n0 + tid];
    __syncthreads();
    for (int i = tid; i < 64 * 128; i += 256) {
        int ci = i & 63, pt = i >> 6;
        atomicAdd(&gsum[((size_t)(b << 15) + sidx[pt]) * 64 + ci], lf[ci * 129 + pt]);
    }
}

// ---------------- sum -> mean, to padded bf16 channels-last ----------------
__global__ __launch_bounds__(256) void k_gridmean_cl(const float* __restrict__ gsum,
                                                     const float* __restrict__ cnt,
                                                     ushort* __restrict__ gpad) {
    int idx = blockIdx.x * 256 + threadIdx.x;     // 4*32768*16
    int q = idx & 15;
    int vox = (idx >> 4) & 32767;
    int b = idx >> 19;
    float c = cnt[(b << 15) + vox];
    float inv = 1.0f / fmaxf(c, 1.0f);
    float4 v = *(const float4*)(gsum + (((size_t)(b << 15) + vox) << 6) + q * 4);
    int zz = vox >> 10, yy = (vox >> 5) & 31, xx = vox & 31;
    size_t o = ((size_t)b * PADV_ + (size_t)(zz + 1) * PPLANE_ + (yy + 1) * 34 + (xx + 1)) * 64 + q * 4;
    i32x2 pk;
    ushort* u = (ushort*)&pk;
    u[0] = f2bf(v.x * inv); u[1] = f2bf(v.y * inv);
    u[2] = f2bf(v.z * inv); u[3] = f2bf(v.w * inv);
    *(i32x2*)(gpad + o) = pk;
}

// ---------------- weight transpose [co][ci][27] f32 -> [27][co][ci] bf16 ----------------
template <int CI>
__global__ __launch_bounds__(256) void k_wtrans(const float* __restrict__ w,
                                                ushort* __restrict__ wt) {
    int idx = blockIdx.x * 256 + threadIdx.x;
    if (idx >= 27 * 128 * CI) return;
    int tap = idx / (128 * CI);
    int rem = idx - tap * 128 * CI;
    int co = rem / CI;
    int ci = rem - co * CI;
    wt[idx] = f2bf(w[((size_t)co * CI + ci) * 27 + tap]);
}

// ---------------- 3^3 conv as K-loop implicit GEMM (2-phase double-buffered) ----------------
// block: 256 pos (1z x 8y x 32x) x 128 co, 512 thr / 8 waves (4 pos-grp x 2 co-grp)
// K = 27*CI, K-step 64. LDS: A[2][256][64] bf16 (32KB x2) + B[2][128][64] (16KB x2) = 96KB
// XOR swizzle: 16B slot j of row r stored at j ^ (r&7)  (both write and read sides)
template <int CI, bool PAD_OUT>
__global__ __launch_bounds__(512, 2) void k_conv(const ushort* __restrict__ inp,
                                                 const ushort* __restrict__ wt,
                                                 const float* __restrict__ bias,
                                                 ushort* __restrict__ outp,
                                                 float* __restrict__ gstats,
                                                 int layer) {
    constexpr int NK = 27 * CI / 64;
    __shared__ i32x4 lds_mem[6144];            // 98304 B
    char* lds = (char*)lds_mem;

    const int yg = blockIdx.x, z0 = blockIdx.y, b = blockIdx.z;
    const int y0 = yg * 8;
    const int tid = threadIdx.x;
    const int w = tid >> 6, l = tid & 63;
    const int lk = l >> 4, lr = l & 15;
    const int wr = w >> 1, wc = w & 1;

    const ushort* actb = inp + (size_t)b * PADV_ * CI;

    // ---- staging constants ----
    int aglb[4], awld[4];
    #pragma unroll
    for (int i = 0; i < 4; ++i) {
        int idx = tid + i * 512;
        int row = idx >> 3, j = idx & 7;
        int py = row >> 5, px = row & 31;
        aglb[i] = (z0 * PPLANE_ + (y0 + py) * 34 + px) * CI + j * 8;
        awld[i] = row * 128 + ((j ^ (row & 7)) << 4);
    }
    int bglb[2], bwld[2];
    #pragma unroll
    for (int i = 0; i < 2; ++i) {
        int idx = tid + i * 512;
        int co = idx >> 3, j = idx & 7;
        bglb[i] = co * CI + j * 8;
        bwld[i] = co * 128 + ((j ^ (co & 7)) << 4);
    }
    // ---- fragment read offsets ----
    int ard[4][2], brd[4][2];
    #pragma unroll
    for (int i = 0; i < 4; ++i) {
        int pos = wr * 64 + i * 16 + lr;
        #pragma unroll
        for (int kk = 0; kk < 2; ++kk)
            ard[i][kk] = pos * 128 + (((kk * 4 + lk) ^ (pos & 7)) << 4);
    }
    #pragma unroll
    for (int n = 0; n < 4; ++n) {
        int co = wc * 64 + n * 16 + lr;
        #pragma unroll
        for (int kk = 0; kk < 2; ++kk)
            brd[n][kk] = co * 128 + (((kk * 4 + lk) ^ (co & 7)) << 4);
    }

    f32x4 acc[4][4];
    #pragma unroll
    for (int i = 0; i < 4; ++i)
        #pragma unroll
        for (int n = 0; n < 4; ++n)
            acc[i][n] = (f32x4){0.f, 0.f, 0.f, 0.f};

    // ---- prologue: stage K-step 0 (tap 0, delta 0) ----
    i32x4 ar[4], br[2];
    #pragma unroll
    for (int i = 0; i < 4; ++i) ar[i] = *(const i32x4*)(actb + aglb[i]);
    #pragma unroll
    for (int i = 0; i < 2; ++i) br[i] = *(const i32x4*)(wt + bglb[i]);
    #pragma unroll
    for (int i = 0; i < 4; ++i) *(i32x4*)(lds + awld[i]) = ar[i];
    #pragma unroll
    for (int i = 0; i < 2; ++i) *(i32x4*)(lds + 65536 + bwld[i]) = br[i];
    __syncthreads();

    #pragma unroll 2
    for (int ks = 0; ks < NK; ++ks) {
        const int cur = ks & 1;
        const bool more = (ks + 1 < NK);
        if (more) {
            int ksn = ks + 1;
            int tap = (CI == 64) ? ksn : (ksn >> 1);
            int choff = (CI == 64) ? 0 : ((ksn & 1) << 6);
            int fz = tap / 9, r9 = tap - fz * 9;
            int fy = r9 / 3, fx = r9 - fy * 3;
            int adelta = (fz * PPLANE_ + fy * 34 + fx) * CI + choff;
            const ushort* wp = wt + tap * (128 * CI) + choff;
            #pragma unroll
            for (int i = 0; i < 4; ++i) ar[i] = *(const i32x4*)(actb + aglb[i] + adelta);
            #pragma unroll
            for (int i = 0; i < 2; ++i) br[i] = *(const i32x4*)(wp + bglb[i]);
        }
        const char* Ac = lds + cur * 32768;
        const char* Bc = lds + 65536 + cur * 16384;
        #pragma unroll
        for (int kk = 0; kk < 2; ++kk) {
            bf16x8 af[4], bfr[4];
            #pragma unroll
            for (int i = 0; i < 4; ++i) af[i] = *(const bf16x8*)(Ac + ard[i][kk]);
            #pragma unroll
            for (int n = 0; n < 4; ++n) bfr[n] = *(const bf16x8*)(Bc + brd[n][kk]);
            #pragma unroll
            for (int i = 0; i < 4; ++i)
                #pragma unroll
                for (int n = 0; n < 4; ++n)
                    acc[i][n] = __builtin_amdgcn_mfma_f32_16x16x32_bf16(af[i], bfr[n], acc[i][n], 0, 0, 0);
        }
        if (more) {
            char* An = lds + (cur ^ 1) * 32768;
            char* Bn = lds + 65536 + (cur ^ 1) * 16384;
            #pragma unroll
            for (int i = 0; i < 4; ++i) *(i32x4*)(An + awld[i]) = ar[i];
            #pragma unroll
            for (int i = 0; i < 2; ++i) *(i32x4*)(Bn + bwld[i]) = br[i];
            __syncthreads();
        }
    }

    // ---- epilogue: bias + fused GN stats + bf16 pack via LDS + coalesced dump ----
    __syncthreads();
    ushort* outs = (ushort*)lds;
    float bb[4];
    #pragma unroll
    for (int n = 0; n < 4; ++n) bb[n] = bias[wc * 64 + n * 16 + lr];
    float sg[4] = {0.f, 0.f, 0.f, 0.f}, sq[4] = {0.f, 0.f, 0.f, 0.f};
    #pragma unroll
    for (int i = 0; i < 4; ++i) {
        int posb = wr * 64 + i * 16 + lk * 4;
        #pragma unroll
        for (int n = 0; n < 4; ++n) {
            int co = wc * 64 + n * 16 + lr;
            #pragma unroll
            for (int r = 0; r < 4; ++r) {
                float v = acc[i][n][r] + bb[n];
                sg[n] += v; sq[n] += v * v;
                outs[(posb + r) * 128 + co] = f2bf(v);
            }
        }
    }
    #pragma unroll
    for (int off = 1; off < 64; off <<= 1) {
        #pragma unroll
        for (int n = 0; n < 4; ++n) {
            sg[n] += __shfl_xor(sg[n], off);
            sq[n] += __shfl_xor(sq[n], off);
        }
    }
    if (l == 0) {
        int gbase = layer * 32 + b * 8 + wc * 4;
        #pragma unroll
        for (int n = 0; n < 4; ++n) {
            atomicAdd(&gstats[(gbase + n) * 2 + 0], sg[n]);
            atomicAdd(&gstats[(gbase + n) * 2 + 1], sq[n]);
        }
    }
    __syncthreads();
    for (int idx = tid; idx < 4096; idx += 512) {
        int pos = idx >> 4, c8 = idx & 15;
        int yy = y0 + (pos >> 5), xx = pos & 31;
        size_t g;
        if (PAD_OUT)
            g = ((size_t)b * PADV_ + (size_t)(z0 + 1) * PPLANE_ + (yy + 1) * 34 + (xx + 1)) * 128 + c8 * 8;
        else
            g = ((size_t)b * RRR_ + z0 * 1024 + yy * 32 + xx) * 128 + c8 * 8;
        *(i32x4*)(outp + g) = *((i32x4*)lds + idx);
    }
}

// ---------------- GN + SiLU apply (channels-last bf16, padded or flat) ----------------
template <bool PAD>
__global__ __launch_bounds__(256) void k_gn_apply(ushort* __restrict__ x,
                                                  const float* __restrict__ gstats,
                                                  const float* __restrict__ sc,
                                                  const float* __restrict__ bi,
                                                  int layer, float invc) {
    int idx = blockIdx.x * 256 + threadIdx.x;   // 4*32768*16
    int c8 = idx & 15;
    int vox = (idx >> 4) & 32767;
    int b = idx >> 19;
    size_t base;
    if (PAD) {
        int zz = vox >> 10, yy = (vox >> 5) & 31, xx = vox & 31;
        base = ((size_t)b * PADV_ + (size_t)(zz + 1) * PPLANE_ + (yy + 1) * 34 + (xx + 1)) * 128 + c8 * 8;
    } else {
        base = ((size_t)b * RRR_ + vox) * 128 + c8 * 8;
    }
    int g = c8 >> 1;
    float sum = gstats[(layer * 32 + b * 8 + g) * 2 + 0];
    float ssq = gstats[(layer * 32 + b * 8 + g) * 2 + 1];
    float mean = sum * invc;
    float var = ssq * invc - mean * mean;
    float rstd = rsqrtf(var + 1e-5f);
    i32x4 raw = *(i32x4*)(x + base);
    ushort* u = (ushort*)&raw;
    #pragma unroll
    for (int j = 0; j < 8; ++j) {
        int co = c8 * 8 + j;
        float v = bf2f(u[j]);
        v = (v - mean) * rstd * sc[co] + bi[co];
        v = v / (1.f + __expf(-v));
        u[j] = f2bf(v);
    }
    *(i32x4*)(x + base) = raw;
}

// ---------------- point MLP (1x1 conv) + fused GN stats ----------------
__global__ __launch_bounds__(256) void k_point_mlp(const float* __restrict__ feats,
                                                   const float* __restrict__ w,
                                                   const float* __restrict__ pb,
                                                   float* __restrict__ out,
                                                   float* __restrict__ gstats) {
    __shared__ float wl[64 * 132];
    __shared__ float sred[4][16];
    int tid = threadIdx.x;
    for (int i = tid; i < 128 * 64; i += 256) {
        int o = i >> 6, c = i & 63;
        wl[c * 132 + o] = w[i];
    }
    __syncthreads();
    int gid = blockIdx.x * 256 + tid;
    int b = gid >> 16, n = gid & (N_ - 1);
    const float* fb = feats + (size_t)b * 64 * N_ + n;
    float acc[128];
    #pragma unroll
    for (int o = 0; o < 128; ++o) acc[o] = 0.f;
    for (int c = 0; c < 64; ++c) {
        float f = fb[(size_t)c * N_];
        const float4* wr4 = (const float4*)&wl[c * 132];
        #pragma unroll
        for (int o4 = 0; o4 < 32; ++o4) {
            float4 wv = wr4[o4];
            acc[4 * o4 + 0] = fmaf(f, wv.x, acc[4 * o4 + 0]);
            acc[4 * o4 + 1] = fmaf(f, wv.y, acc[4 * o4 + 1]);
            acc[4 * o4 + 2] = fmaf(f, wv.z, acc[4 * o4 + 2]);
            acc[4 * o4 + 3] = fmaf(f, wv.w, acc[4 * o4 + 3]);
        }
    }
    float* ob = out + (size_t)b * 128 * N_ + n;
    float sg[8] = {0.f}, sq[8] = {0.f};
    #pragma unroll
    for (int o = 0; o < 128; ++o) {
        float v = acc[o] + pb[o];
        ob[(size_t)o * N_] = v;
        sg[o >> 4] += v;
        sq[o >> 4] += v * v;
    }
    #pragma unroll
    for (int off = 1; off < 64; off <<= 1) {
        #pragma unroll
        for (int g = 0; g < 8; ++g) {
            sg[g] += __shfl_xor(sg[g], off);
            sq[g] += __shfl_xor(sq[g], off);
        }
    }
    int wv = tid >> 6, l = tid & 63;
    if (l == 0) {
        #pragma unroll
        for (int g = 0; g < 8; ++g) { sred[wv][g] = sg[g]; sred[wv][8 + g] = sq[g]; }
    }
    __syncthreads();
    if (tid < 16) {
        float v = sred[0][tid] + sred[1][tid] + sred[2][tid] + sred[3][tid];
        int g = tid & 7, part = tid >> 3;
        atomicAdd(&gstats[(64 + b * 8 + g) * 2 + part], v);
    }
}

// ---------------- devoxelize + point GN/SiLU + add ----------------
__global__ __launch_bounds__(256) void k_devox_final(const float* __restrict__ nc,
                                                     const ushort* __restrict__ ht,
                                                     const float* __restrict__ gstats,
                                                     const float* __restrict__ scale,
                                                     const float* __restrict__ bias,
                                                     float* __restrict__ out) {
    __shared__ float vp[64][129];
    __shared__ int sidx[64][8];
    __shared__ float swt[64][8];
    int tid = threadIdx.x;
    int blk = blockIdx.x;               // B * N/64 = 4096
    int b = blk >> 10;
    int n0 = (blk & 1023) * 64;
    if (tid < 64) {
        int n = n0 + tid;
        float f0 = nc[(size_t)b * 3 * N_ + n];
        float f1 = nc[((size_t)b * 3 + 1) * N_ + n];
        float f2 = nc[((size_t)b * 3 + 2) * N_ + n];
        float l0 = floorf(f0), l1 = floorf(f1), l2 = floorf(f2);
        float r0 = f0 - l0, r1 = f1 - l1, r2 = f2 - l2;
        int i0 = (int)l0, i1 = (int)l1, i2 = (int)l2;
        int h0 = min(i0 + 1, 31), h1 = min(i1 + 1, 31), h2 = min(i2 + 1, 31);
        #pragma unroll
        for (int k = 0; k < 8; ++k) {
            int dx = (k >> 2) & 1, dy = (k >> 1) & 1, dz = k & 1;
            int ix = dx ? h0 : i0, iy = dy ? h1 : i1, iz = dz ? h2 : i2;
            float w = (dx ? r0 : 1.f - r0) * (dy ? r1 : 1.f - r1) * (dz ? r2 : 1.f - r2);
            sidx[tid][k] = (ix * 32 + iy) * 32 + iz;
            swt[tid][k] = w;
        }
    }
    __syncthreads();
    const ushort* hb = ht + (size_t)b * RRR_ * 128;
    for (int t = tid; t < 64 * 16; t += 256) {
        int c8 = t & 15, pt = t >> 4;
        float a[8] = {0.f, 0.f, 0.f, 0.f, 0.f, 0.f, 0.f, 0.f};
        #pragma unroll
        for (int k = 0; k < 8; ++k) {
            i32x4 raw = *(const i32x4*)(hb + (size_t)sidx[pt][k] * 128 + c8 * 8);
            ushort* u = (ushort*)&raw;
            float wk = swt[pt][k];
            #pragma unroll
            for (int j = 0; j < 8; ++j)
                a[j] = fmaf(wk, bf2f(u[j]), a[j]);
        }
        #pragma unroll
        for (int j = 0; j < 8; ++j)
            vp[pt][c8 * 8 + j] = a[j];
    }
    __syncthreads();
    const float invc = 1.0f / (16.0f * (float)N_);
    for (int t = tid; t < 64 * 128; t += 256) {
        int nl = t & 63;
        int c = t >> 6;
        int g = c >> 4;
        float sum = gstats[(64 + b * 8 + g) * 2 + 0];
        float ssq = gstats[(64 + b * 8 + g) * 2 + 1];
        float mean = sum * invc;
        float var = ssq * invc - mean * mean;
        float rstd = rsqrtf(var + 1e-5f);
        size_t o = ((size_t)(b * 128 + c)) * N_ + n0 + nl;
        float v = (out[o] - mean) * rstd * scale[c] + bias[c];
        v = v / (1.f + __expf(-v));
        out[o] = v + vp[nl][c];
    }
}

extern "C" void kernel_launch(void* const* d_in, const int* in_sizes, int n_in,
                              void* d_out, int out_size, void* d_ws, size_t ws_size,
                              hipStream_t stream) {
    const float* coords   = (const float*)d_in[0];
    const float* features = (const float*)d_in[1];
    const float* conv1_w  = (const float*)d_in[2];
    const float* conv1_b  = (const float*)d_in[3];
    const float* gn1_s    = (const float*)d_in[4];
    const float* gn1_b    = (const float*)d_in[5];
    const float* conv2_w  = (const float*)d_in[6];
    const float* conv2_b  = (const float*)d_in[7];
    const float* gn2_s    = (const float*)d_in[8];
    const float* gn2_b    = (const float*)d_in[9];
    const float* point_w  = (const float*)d_in[10];
    const float* point_b  = (const float*)d_in[11];
    const float* pgn_s    = (const float*)d_in[12];
    const float* pgn_b    = (const float*)d_in[13];
    float* out = (float*)d_out;
    float* ws = (float*)d_ws;

    float*  nc     = ws + OFF_NC;
    int*    vidx   = (int*)(ws + OFF_VIDX);
    ushort* wt1    = (ushort*)(ws + OFF_WT1);
    ushort* wt2    = (ushort*)(ws + OFF_WT2);
    ushort* c2out  = (ushort*)(ws + OFF_C2OUT);
    float*  cnt    = ws + OFF_CNT;
    float*  gsum   = ws + OFF_GSUM;
    ushort* gpad   = (ushort*)(ws + OFF_GPAD);
    ushort* act1   = (ushort*)(ws + OFF_ACT1);
    float*  gstats = ws + OFF_GSTATS;
    float*  bstats = ws + OFF_BSTATS;

    const float invc = 1.0f / (float)(RRR_ * 16);

    hipMemsetAsync(cnt, 0, MEMSET_FLOATS * sizeof(float), stream);

    k_coord_sum<<<dim3(64, B_), 256, 0, stream>>>(coords, bstats);
    k_coord_max<<<dim3(64, B_), 256, 0, stream>>>(coords, bstats);
    k_point_prep<<<B_ * N_ / 256, 256, 0, stream>>>(coords, bstats, nc, vidx, cnt);
    k_scatter_cl<<<dim3(N_ / 128, B_), 256, 0, stream>>>(features, vidx, gsum);
    k_gridmean_cl<<<B_ * RRR_ * 16 / 256, 256, 0, stream>>>(gsum, cnt, gpad);

    k_wtrans<64><<<(27 * 128 * 64 + 255) / 256, 256, 0, stream>>>(conv1_w, wt1);
    k_wtrans<128><<<(27 * 128 * 128 + 255) / 256, 256, 0, stream>>>(conv2_w, wt2);

    k_conv<64, true><<<dim3(4, 32, B_), 512, 0, stream>>>(gpad, wt1, conv1_b, act1, gstats, 0);
    k_gn_apply<true><<<B_ * RRR_ * 16 / 256, 256, 0, stream>>>(act1, gstats, gn1_s, gn1_b, 0, invc);

    k_conv<128, false><<<dim3(4, 32, B_), 512, 0, stream>>>(act1, wt2, conv2_b, c2out, gstats, 1);
    k_gn_apply<false><<<B_ * RRR_ * 16 / 256, 256, 0, stream>>>(c2out, gstats, gn2_s, gn2_b, 1, invc);

    k_point_mlp<<<B_ * N_ / 256, 256, 0, stream>>>(features, point_w, point_b, out, gstats);
    k_devox_final<<<B_ * N_ / 64, 256, 0, stream>>>(nc, c2out, gstats, pgn_s, pgn_b, out);
}